// Round 5
// baseline (506.464 us; speedup 1.0000x reference)
//
#include <hip/hip_runtime.h>
#include <stdint.h>

typedef unsigned short U16;
typedef __bf16 bf16x8 __attribute__((ext_vector_type(8)));
typedef unsigned short us8 __attribute__((ext_vector_type(8)));
typedef float f32x4 __attribute__((ext_vector_type(4)));

__device__ __forceinline__ U16 f2bf(float f) {
    unsigned u = __builtin_bit_cast(unsigned, f);
    unsigned r = (u + 0x7fff + ((u >> 16) & 1)) >> 16;
    return (U16)r;
}
__device__ __forceinline__ U16 f2bf_fast(float f) {   // round-half-up, for positive non-NaN
    return (U16)((__builtin_bit_cast(unsigned, f) + 0x8000u) >> 16);
}
__device__ __forceinline__ float bf2f(U16 v) {
    return __builtin_bit_cast(float, (unsigned)v << 16);
}
__device__ __forceinline__ bf16x8 ld8(const U16* p) { return __builtin_bit_cast(bf16x8, *(const us8*)p); }

// async global->LDS, 16B per lane; lds base wave-uniform, HW scatters lane i at base+i*16
__device__ __forceinline__ void async16(const U16* g, U16* l) {
    auto* gp = (const __attribute__((address_space(1))) U16*)g;
    auto* lp = (__attribute__((address_space(3))) U16*)(uintptr_t)(uint32_t)(uintptr_t)l;
    __builtin_amdgcn_global_load_lds(gp, lp, 16, 0, 0);
}

// ---------------- merged weight transpose: dst[noff+n][kk] = bf16(src[kk-koff][n]), zero-padded
struct WEnt { const float* src; U16* dst; int K, N, Kpad, Npad, koff, noff, tiles; };
struct WTable { WEnt e[13]; };

__global__ __launch_bounds__(256) void wtrans_all(WTable t) {
    int bx = blockIdx.x, ei = 0;
    while (bx >= t.e[ei].tiles) { bx -= t.e[ei].tiles; ei++; }
    const WEnt E = t.e[ei];
    const int ntn = E.Npad >> 5;
    const int n0 = (bx % ntn) * 32, k0 = (bx / ntn) * 32;
    __shared__ float tile[32][33];
    const int tx = threadIdx.x & 31, ty = threadIdx.x >> 5;
#pragma unroll
    for (int i = 0; i < 4; i++) {
        int kk = k0 + ty + i * 8, n = n0 + tx;
        int k = kk - E.koff;
        float v = (k >= 0 && k < E.K && n < E.N) ? E.src[(size_t)k * E.N + n] : 0.f;
        tile[ty + i * 8][tx] = v;
    }
    __syncthreads();
#pragma unroll
    for (int i = 0; i < 4; i++) {
        int n = n0 + ty + i * 8, kk = k0 + tx;
        E.dst[(size_t)(E.noff + n) * E.Kpad + kk] = f2bf(tile[tx][ty + i * 8]);
    }
}

// ---------------- fp32 -> bf16 convert
__global__ __launch_bounds__(256) void f2bf_k(const float* __restrict__ in, U16* __restrict__ out, int n) {
    int i = (blockIdx.x * 256 + threadIdx.x) * 4;
    if (i < n) {
        float4 v = *(const float4*)(in + i);
        out[i + 0] = f2bf(v.x); out[i + 1] = f2bf(v.y);
        out[i + 2] = f2bf(v.z); out[i + 3] = f2bf(v.w);
    }
}

// ---------------- reduce 4 fp32 partials [4][4096*128] -> bf16
__global__ __launch_bounds__(256) void cq_reduce(const float* __restrict__ p, U16* __restrict__ out) {
    int i = (blockIdx.x * 256 + threadIdx.x) * 4;
    const float4 a = *(const float4*)(p + i);
    const float4 b = *(const float4*)(p + 524288 + i);
    const float4 c = *(const float4*)(p + 2 * 524288 + i);
    const float4 d = *(const float4*)(p + 3 * 524288 + i);
    out[i + 0] = f2bf(a.x + b.x + c.x + d.x);
    out[i + 1] = f2bf(a.y + b.y + c.y + d.y);
    out[i + 2] = f2bf(a.z + b.z + c.z + d.z);
    out[i + 3] = f2bf(a.w + b.w + c.w + d.w);
}

// ---------------- RMSNorm: fp32 row (1024) -> bf16
__global__ __launch_bounds__(256) void rmsnorm_k(const float* __restrict__ x, const float* __restrict__ w,
                                                 U16* __restrict__ h) {
    const int row = blockIdx.x, tid = threadIdx.x;
    const float4 v = *(const float4*)(x + (size_t)row * 1024 + tid * 4);
    float ss = v.x * v.x + v.y * v.y + v.z * v.z + v.w * v.w;
#pragma unroll
    for (int o = 32; o > 0; o >>= 1) ss += __shfl_xor(ss, o);
    __shared__ float red[4];
    if ((tid & 63) == 0) red[tid >> 6] = ss;
    __syncthreads();
    float tot = red[0] + red[1] + red[2] + red[3];
    float sc = rsqrtf(tot * (1.0f / 1024.0f) + 1e-6f);
    const float4 wv = *(const float4*)(w + tid * 4);
    U16* hp = h + (size_t)row * 1024 + tid * 4;
    hp[0] = f2bf(v.x * sc * wv.x); hp[1] = f2bf(v.y * sc * wv.y);
    hp[2] = f2bf(v.z * sc * wv.z); hp[3] = f2bf(v.w * sc * wv.w);
}

// ---------------- merged uq/uk + uv GEMM from cq [4096][128], K=128
// grid (24, 32): x<16 -> qkb bf16 [4096][2048]; x>=16 -> vt transposed bf16 [1024][4096]
__global__ __launch_bounds__(256) void qkuv_gemm(const U16* __restrict__ A, const U16* __restrict__ Wuqk,
                                                 const U16* __restrict__ Wuv,
                                                 U16* __restrict__ qkb, U16* __restrict__ vt) {
    __shared__ __align__(16) U16 As[2][128 * 32];
    __shared__ __align__(16) U16 Bs[2][128 * 32];
    __shared__ __align__(16) U16 Ts[4][64 * 80];
    const int tid = threadIdx.x;
    const bool isuv = blockIdx.x >= 16;
    const U16* Bt = isuv ? Wuv : Wuqk;
    const int n0 = (isuv ? blockIdx.x - 16 : blockIdx.x) * 128;
    const int m0 = blockIdx.y * 128;
    const int wave = tid >> 6, lane = tid & 63, l16 = lane & 15, quad = lane >> 4;
    const int wm = (wave >> 1) * 64, wn = (wave & 1) * 64;
    const int sr = lane >> 2, sc = (lane & 3) * 8;
    const U16* gA = A + (size_t)(m0 + wave * 32 + sr) * 128 + sc;
    const U16* gB = Bt + (size_t)(n0 + wave * 32 + sr) * 128 + sc;
    f32x4 acc[4][4] = {};
    for (int kt = 0; kt < 128; kt += 64) {
        __syncthreads();
#pragma unroll
        for (int p = 0; p < 2; p++) {
            const int o = kt + p * 32;
            async16(gA + o, &As[p][(wave * 32) * 32]);
            async16(gA + 16 * 128 + o, &As[p][(wave * 32 + 16) * 32]);
            async16(gB + o, &Bs[p][(wave * 32) * 32]);
            async16(gB + 16 * 128 + o, &Bs[p][(wave * 32 + 16) * 32]);
        }
        __syncthreads();
#pragma unroll
        for (int p = 0; p < 2; p++) {
            bf16x8 af[4], bfr[4];
#pragma unroll
            for (int i = 0; i < 4; i++) {
                af[i]  = ld8(&As[p][(wm + i * 16 + l16) * 32 + quad * 8]);
                bfr[i] = ld8(&Bs[p][(wn + i * 16 + l16) * 32 + quad * 8]);
            }
#pragma unroll
            for (int mi = 0; mi < 4; mi++)
#pragma unroll
                for (int ni = 0; ni < 4; ni++)
                    acc[mi][ni] = __builtin_amdgcn_mfma_f32_16x16x32_bf16(af[mi], bfr[ni], acc[mi][ni], 0, 0, 0);
        }
    }
    if (isuv) {
        // per-wave LDS transpose -> coalesced 16B stores along m into vt [1024][4096]
        U16* T = Ts[wave];
#pragma unroll
        for (int mi = 0; mi < 4; mi++)
#pragma unroll
            for (int ni = 0; ni < 4; ni++)
#pragma unroll
                for (int r = 0; r < 4; r++)
                    T[(ni * 16 + l16) * 80 + mi * 16 + quad * 4 + r] = f2bf(acc[mi][ni][r]);
#pragma unroll
        for (int c = 0; c < 8; c++) {
            int nloc = (lane >> 3) + 8 * c, mloc = (lane & 7) * 8;
            us8 v = *(const us8*)&T[nloc * 80 + mloc];
            *(us8*)&vt[(size_t)(n0 + wn + nloc) * 4096 + (m0 + wm + mloc)] = v;
        }
    } else {
#pragma unroll
        for (int mi = 0; mi < 4; mi++)
#pragma unroll
            for (int r = 0; r < 4; r++) {
                int m = m0 + wm + mi * 16 + quad * 4 + r;
#pragma unroll
                for (int ni = 0; ni < 4; ni++)
                    qkb[(size_t)m * 2048 + n0 + wn + ni * 16 + l16] = f2bf(acc[mi][ni][r]);
            }
    }
}

// ---------------- 64x128 GEMM, quad-panel K (logical BK=128)
// EPI 0: bf16. EPI 1: fp32 = resid + acc. EPI 5: fp32 partial at Cout + z*524288 (no resid).
template <int EPI>
__global__ __launch_bounds__(256) void gemm_m64(const U16* __restrict__ A, const U16* __restrict__ Bt,
                                                void* __restrict__ Cout, const float* __restrict__ resid,
                                                int M, int N, int K, int lda, int ldb, int ldc) {
    __shared__ __align__(16) U16 As[4][64 * 32];
    __shared__ __align__(16) U16 Bs[4][128 * 32];
    const int tid = threadIdx.x;
    const int m0 = blockIdx.y * 64, n0 = blockIdx.x * 128;
    const int k0 = blockIdx.z * K;
    const int wave = tid >> 6, lane = tid & 63, l16 = lane & 15, quad = lane >> 4;
    const int wm = (wave >> 1) * 32, wn = (wave & 1) * 64;
    const int sr = lane >> 2, sc = (lane & 3) * 8;
    const U16* gA = A + (size_t)(m0 + wave * 16 + sr) * lda + sc + k0;
    const U16* gB = Bt + (size_t)(n0 + wave * 32 + sr) * ldb + sc + k0;
    f32x4 acc[2][4] = {};
    for (int kt = 0; kt < K; kt += 128) {
        __syncthreads();
#pragma unroll
        for (int p = 0; p < 4; p++) {
            const int o = kt + p * 32;
            async16(gA + o, &As[p][(wave * 16) * 32]);
            async16(gB + o, &Bs[p][(wave * 32) * 32]);
            async16(gB + (size_t)16 * ldb + o, &Bs[p][(wave * 32 + 16) * 32]);
        }
        __syncthreads();
#pragma unroll
        for (int p = 0; p < 4; p++) {
            bf16x8 af[2], bfr[4];
#pragma unroll
            for (int i = 0; i < 2; i++)
                af[i] = ld8(&As[p][(wm + i * 16 + l16) * 32 + quad * 8]);
#pragma unroll
            for (int i = 0; i < 4; i++)
                bfr[i] = ld8(&Bs[p][(wn + i * 16 + l16) * 32 + quad * 8]);
#pragma unroll
            for (int mi = 0; mi < 2; mi++)
#pragma unroll
                for (int ni = 0; ni < 4; ni++)
                    acc[mi][ni] = __builtin_amdgcn_mfma_f32_16x16x32_bf16(af[mi], bfr[ni], acc[mi][ni], 0, 0, 0);
        }
    }
#pragma unroll
    for (int mi = 0; mi < 2; mi++) {
#pragma unroll
        for (int r = 0; r < 4; r++) {
            int m = m0 + wm + mi * 16 + quad * 4 + r;
#pragma unroll
            for (int ni = 0; ni < 4; ni++) {
                int n = n0 + wn + ni * 16 + l16;
                float val = acc[mi][ni][r];
                if (EPI == 0) ((U16*)Cout)[(size_t)m * ldc + n] = f2bf(val);
                else if (EPI == 1) ((float*)Cout)[(size_t)m * ldc + n] = resid[(size_t)m * ldc + n] + val;
                else if (EPI == 5) ((float*)Cout)[(size_t)blockIdx.z * 524288 + (size_t)m * ldc + n] = val;
            }
        }
    }
}

// ---------------- merged qc + kvc GEMM (both EPI0, K=1024, lda=ldb=1024)
// 768 blocks: [0,512) -> qcb [4096][1024]; [512,768) -> kvcb [1024][2048]
__global__ __launch_bounds__(256) void qckv_gemm(const U16* __restrict__ hbuf, const U16* __restrict__ Wqc,
                                                 const U16* __restrict__ memb, const U16* __restrict__ Wkvc,
                                                 U16* __restrict__ qcb, U16* __restrict__ kvcb) {
    __shared__ __align__(16) U16 As[4][64 * 32];
    __shared__ __align__(16) U16 Bs[4][128 * 32];
    const int tid = threadIdx.x, bid = blockIdx.x;
    const U16 *A, *Bt; U16* C; int m0, n0, ldc;
    if (bid < 512) { A = hbuf; Bt = Wqc;  C = qcb;  m0 = (bid >> 3) * 64; n0 = (bid & 7) * 128;  ldc = 1024; }
    else { int b2 = bid - 512; A = memb; Bt = Wkvc; C = kvcb; m0 = (b2 >> 4) * 64; n0 = (b2 & 15) * 128; ldc = 2048; }
    const int wave = tid >> 6, lane = tid & 63, l16 = lane & 15, quad = lane >> 4;
    const int wm = (wave >> 1) * 32, wn = (wave & 1) * 64;
    const int sr = lane >> 2, sc = (lane & 3) * 8;
    const U16* gA = A + (size_t)(m0 + wave * 16 + sr) * 1024 + sc;
    const U16* gB = Bt + (size_t)(n0 + wave * 32 + sr) * 1024 + sc;
    f32x4 acc[2][4] = {};
    for (int kt = 0; kt < 1024; kt += 128) {
        __syncthreads();
#pragma unroll
        for (int p = 0; p < 4; p++) {
            const int o = kt + p * 32;
            async16(gA + o, &As[p][(wave * 16) * 32]);
            async16(gB + o, &Bs[p][(wave * 32) * 32]);
            async16(gB + 16 * 1024 + o, &Bs[p][(wave * 32 + 16) * 32]);
        }
        __syncthreads();
#pragma unroll
        for (int p = 0; p < 4; p++) {
            bf16x8 af[2], bfr[4];
#pragma unroll
            for (int i = 0; i < 2; i++)
                af[i] = ld8(&As[p][(wm + i * 16 + l16) * 32 + quad * 8]);
#pragma unroll
            for (int i = 0; i < 4; i++)
                bfr[i] = ld8(&Bs[p][(wn + i * 16 + l16) * 32 + quad * 8]);
#pragma unroll
            for (int mi = 0; mi < 2; mi++)
#pragma unroll
                for (int ni = 0; ni < 4; ni++)
                    acc[mi][ni] = __builtin_amdgcn_mfma_f32_16x16x32_bf16(af[mi], bfr[ni], acc[mi][ni], 0, 0, 0);
        }
    }
#pragma unroll
    for (int mi = 0; mi < 2; mi++)
#pragma unroll
        for (int r = 0; r < 4; r++) {
            int m = m0 + wm + mi * 16 + quad * 4 + r;
#pragma unroll
            for (int ni = 0; ni < 4; ni++)
                C[(size_t)m * ldc + n0 + wn + ni * 16 + l16] = f2bf(acc[mi][ni][r]);
        }
}

// ---------------- fused FFN1, 256x256 deep-pipelined, per-phase quadrant schedule (m201-style)
// Each K-tile (BK=64) runs 4 phases: {ds_read quadrant operands -> barrier -> setprio MFMA16 -> barrier}.
// Counted vmcnt(8) at tile top (2 tiles in flight); STAGE after tile-end barrier refills the buffer.
__global__ __launch_bounds__(512, 2) void ffn1_8ph(const U16* __restrict__ A, const U16* __restrict__ Wgu,
                                                   U16* __restrict__ Cout) {
    __shared__ __align__(16) U16 As[2][256 * 64];
    __shared__ __align__(16) U16 Bs[2][256 * 64];
    const int tid = threadIdx.x;
    const int wid = tid >> 6, lane = tid & 63;
    const int l16 = lane & 15, quad = lane >> 4;
    const int n0 = blockIdx.x * 128;          // output col tile
    const int m0 = blockIdx.y * 256;          // row tile
    const int wr = wid >> 2, wc = wid & 3;
    const int wm = wr * 128;                  // wave m offset in tile
    const int wn = wc * 64;                   // wave B-row offset in tile
    const int srow = lane >> 3;               // 0..7
    const int schunk = (lane & 7) ^ srow;     // inverse-swizzled source chunk
    const U16* gA = A + (size_t)(m0 + wid * 32 + srow) * 1024 + schunk * 8;
    const U16* gB = Wgu + (size_t)((wid & 1) * 4096 + n0 + (wid >> 1) * 32 + srow) * 1024 + schunk * 8;

    auto STAGE = [&](int buf, int kt) {       // 8 global_load_lds per wave
        U16* la = &As[buf][(wid * 32) * 64];
        U16* lb = &Bs[buf][(wid * 32) * 64];
        const U16* pa = gA + kt;
        const U16* pb = gB + kt;
#pragma unroll
        for (int j = 0; j < 4; ++j) {
            async16(pa + j * 8 * 1024, la + j * 8 * 64);
            async16(pb + j * 8 * 1024, lb + j * 8 * 64);
        }
    };

    f32x4 acc[8][4] = {};                     // [mi][ni]; ni 0,1 = gate (b0), ni 2,3 = up (b1)

    auto TILE = [&](int buf) {
        const U16* Ab = &As[buf][0];
        const U16* Bb = &Bs[buf][0];
        const int cx = l16 & 7;               // read-side swizzle XOR
        bf16x8 a0[4][2], a1[4][2], b0[2][2], b1[2][2];
        // ---- phase 0: read a0 + b0; MFMA Q00 (acc[0..3][0..1])
#pragma unroll
        for (int mi = 0; mi < 4; ++mi)
#pragma unroll
            for (int kh = 0; kh < 2; ++kh)
                a0[mi][kh] = ld8(&Ab[(wm + mi * 16 + l16) * 64 + (((kh * 4 + quad) ^ cx) << 3)]);
#pragma unroll
        for (int ni = 0; ni < 2; ++ni)
#pragma unroll
            for (int kh = 0; kh < 2; ++kh)
                b0[ni][kh] = ld8(&Bb[(wn + ni * 16 + l16) * 64 + (((kh * 4 + quad) ^ cx) << 3)]);
        __builtin_amdgcn_s_barrier();
        __builtin_amdgcn_s_setprio(1);
#pragma unroll
        for (int mi = 0; mi < 4; ++mi)
#pragma unroll
            for (int ni = 0; ni < 2; ++ni)
#pragma unroll
                for (int kh = 0; kh < 2; ++kh)
                    acc[mi][ni] = __builtin_amdgcn_mfma_f32_16x16x32_bf16(a0[mi][kh], b0[ni][kh], acc[mi][ni], 0, 0, 0);
        __builtin_amdgcn_s_setprio(0);
        __builtin_amdgcn_s_barrier();
        // ---- phase 1: read b1; MFMA Q01 (acc[0..3][2..3])
#pragma unroll
        for (int ni = 0; ni < 2; ++ni)
#pragma unroll
            for (int kh = 0; kh < 2; ++kh)
                b1[ni][kh] = ld8(&Bb[(wn + 32 + ni * 16 + l16) * 64 + (((kh * 4 + quad) ^ cx) << 3)]);
        __builtin_amdgcn_s_barrier();
        __builtin_amdgcn_s_setprio(1);
#pragma unroll
        for (int mi = 0; mi < 4; ++mi)
#pragma unroll
            for (int ni = 0; ni < 2; ++ni)
#pragma unroll
                for (int kh = 0; kh < 2; ++kh)
                    acc[mi][2 + ni] = __builtin_amdgcn_mfma_f32_16x16x32_bf16(a0[mi][kh], b1[ni][kh], acc[mi][2 + ni], 0, 0, 0);
        __builtin_amdgcn_s_setprio(0);
        __builtin_amdgcn_s_barrier();
        // ---- phase 2: read a1; MFMA Q11 (acc[4..7][2..3])
#pragma unroll
        for (int mi = 0; mi < 4; ++mi)
#pragma unroll
            for (int kh = 0; kh < 2; ++kh)
                a1[mi][kh] = ld8(&Ab[(wm + 64 + mi * 16 + l16) * 64 + (((kh * 4 + quad) ^ cx) << 3)]);
        __builtin_amdgcn_s_barrier();
        __builtin_amdgcn_s_setprio(1);
#pragma unroll
        for (int mi = 0; mi < 4; ++mi)
#pragma unroll
            for (int ni = 0; ni < 2; ++ni)
#pragma unroll
                for (int kh = 0; kh < 2; ++kh)
                    acc[4 + mi][2 + ni] = __builtin_amdgcn_mfma_f32_16x16x32_bf16(a1[mi][kh], b1[ni][kh], acc[4 + mi][2 + ni], 0, 0, 0);
        __builtin_amdgcn_s_setprio(0);
        __builtin_amdgcn_s_barrier();
        // ---- phase 3: MFMA Q10 (acc[4..7][0..1]) — operands already in regs
        __builtin_amdgcn_s_setprio(1);
#pragma unroll
        for (int mi = 0; mi < 4; ++mi)
#pragma unroll
            for (int ni = 0; ni < 2; ++ni)
#pragma unroll
                for (int kh = 0; kh < 2; ++kh)
                    acc[4 + mi][ni] = __builtin_amdgcn_mfma_f32_16x16x32_bf16(a1[mi][kh], b0[ni][kh], acc[4 + mi][ni], 0, 0, 0);
        __builtin_amdgcn_s_setprio(0);
    };

    // pipeline: 16 K-tiles, 2 in flight (16 loads/wave), vmcnt(8) at tile top
    STAGE(0, 0);
    STAGE(1, 64);
#pragma unroll 1
    for (int t = 0; t < 16; ++t) {
        if (t == 15) asm volatile("s_waitcnt vmcnt(0)" ::: "memory");
        else         asm volatile("s_waitcnt vmcnt(8)" ::: "memory");
        __builtin_amdgcn_s_barrier();
        __builtin_amdgcn_sched_barrier(0);
        TILE(t & 1);
        __builtin_amdgcn_s_barrier();         // all waves' reads of buf complete (lgkm-waited per wave)
        if (t < 14) STAGE(t & 1, (t + 2) * 64);
    }

#pragma unroll
    for (int mi = 0; mi < 8; ++mi)
#pragma unroll
        for (int r = 0; r < 4; ++r) {
            int m = m0 + wm + mi * 16 + quad * 4 + r;
#pragma unroll
            for (int ni = 0; ni < 2; ++ni) {
                int col = n0 + wc * 32 + ni * 16 + l16;
                float g = acc[mi][ni][r], u = acc[mi][ni + 2][r];
                float act = g / (1.f + __expf(-g)) * u;
                Cout[(size_t)m * 4096 + col] = f2bf(act);
            }
        }
}

// ---------------- flash self-attention v4: LDS-staged K/V, double-buffered, counted vmcnt
// Block = 128 q rows (grid 512 = 16 Tq x 32 bh, T descending). 4 waves; wave w owns q-row
// groups {q0 + w*16, q0 + 64 + w*16}. j-tiles of 32 staged cooperatively:
//   K tile [32][64] bf16 (chunk ^= row&7 swizzle), V tile [64][32] bf16 (chunk ^= (row&3)^((row>>2)&3)).
// global_load_lds dest is linear, so the swizzle is applied to the per-lane GLOBAL source
// (both-sides rule) and re-applied on the ds_read side.
__global__ __launch_bounds__(256, 3) void flash_self4(const U16* __restrict__ QK, const U16* __restrict__ Vt,
                                                      U16* __restrict__ Og) {
    __shared__ __align__(16) U16 Ks[2][32 * 64];
    __shared__ __align__(16) U16 Vs[2][64 * 32];
    __shared__ __align__(16) U16 Ps[4][1280];
    const int wave = threadIdx.x >> 6, lane = threadIdx.x & 63;
    const int l16 = lane & 15, quad = lane >> 4;
    const int bx = blockIdx.x;
    const int T = 15 - (bx >> 5);             // heavy tiles first
    const int bh = bx & 31, b = bh >> 4, h = bh & 15;
    const int q0 = T * 128;
    const int NT = 4 * T + 4;                 // number of 32-wide j-tiles
    const int G0 = q0 + wave * 16, G1 = q0 + 64 + wave * 16;
    // Q fragments (4 global loads, complete before first TILE via the vmcnt(2) below)
    bf16x8 aq[2][2];
    {
        const size_t r0 = (size_t)(b * 2048 + G0 + l16) * 2048 + h * 64;
        const size_t r1 = (size_t)(b * 2048 + G1 + l16) * 2048 + h * 64;
        aq[0][0] = ld8(QK + r0 + quad * 8); aq[0][1] = ld8(QK + r0 + 32 + quad * 8);
        aq[1][0] = ld8(QK + r1 + quad * 8); aq[1][1] = ld8(QK + r1 + 32 + quad * 8);
    }
    // staging source addresses (inverse-swizzled)
    const int krow = wave * 8 + (lane >> 3);                               // K tile row
    const int kchunk = (lane & 7) ^ (lane >> 3);                           // ^ (krow&7)
    const U16* gK = QK + (size_t)(b * 2048 + krow) * 2048 + 1024 + h * 64 + kchunk * 8;
    const int vrow = wave * 16 + (lane >> 2);                              // V tile row (d)
    const int vchunk = (lane & 3) ^ ((lane >> 2) & 3) ^ ((lane >> 4) & 3); // ^ (vr&3)^((vr>>2)&3)
    const U16* gV = Vt + (size_t)(h * 64 + vrow) * 4096 + b * 2048 + vchunk * 8;

    auto STAGE = [&](int buf, int j0) {       // 2 global_load_lds per wave
        async16(gK + (size_t)j0 * 2048, &Ks[buf][(wave * 8) * 64]);
        async16(gV + j0, &Vs[buf][(wave * 16) * 32]);
    };

    f32x4 o[2][4] = {};
    float ls[2][4] = {};
    U16* Pw = Ps[wave];
    const int prd = l16 * 40 + ((quad ^ (l16 >> 2)) << 3);

    auto TILE = [&](int buf, int j0) {
        // K fragments: row jh*16+l16, chunk (kh*4+quad)^(l16&7)
        bf16x8 kf[2][2];
#pragma unroll
        for (int jh = 0; jh < 2; ++jh)
#pragma unroll
            for (int kh = 0; kh < 2; ++kh)
                kf[jh][kh] = ld8(&Ks[buf][(jh * 16 + l16) * 64 + (((kh * 4 + quad) ^ (l16 & 7)) << 3)]);
        // V fragments: row dg*16+l16, chunk quad^(l16&3)^((l16>>2)&3)
        bf16x8 vf[4];
#pragma unroll
        for (int dg = 0; dg < 4; ++dg)
            vf[dg] = ld8(&Vs[buf][(dg * 16 + l16) * 32 + ((quad ^ (l16 & 3) ^ ((l16 >> 2) & 3)) << 3)]);
#pragma unroll
        for (int g = 0; g < 2; ++g) {
            const int G = g ? G1 : G0;
            if (j0 < G + 16) {                // group has unmasked rows in this tile
                f32x4 s0 = {}, s1 = {};
                __builtin_amdgcn_s_setprio(1);
                s0 = __builtin_amdgcn_mfma_f32_16x16x32_bf16(aq[g][0], kf[0][0], s0, 0, 0, 0);
                s0 = __builtin_amdgcn_mfma_f32_16x16x32_bf16(aq[g][1], kf[0][1], s0, 0, 0, 0);
                s1 = __builtin_amdgcn_mfma_f32_16x16x32_bf16(aq[g][0], kf[1][0], s1, 0, 0, 0);
                s1 = __builtin_amdgcn_mfma_f32_16x16x32_bf16(aq[g][1], kf[1][1], s1, 0, 0, 0);
                __builtin_amdgcn_s_setprio(0);
                float p0[4], p1[4];
                if (j0 + 32 > G) {            // diagonal tile: apply causal mask
#pragma unroll
                    for (int r = 0; r < 4; ++r) {
                        int qg = G + quad * 4 + r;
                        p0[r] = (j0 + l16 <= qg) ? __expf(fminf(s0[r] * 0.125f, 30.f)) : 0.f;
                        p1[r] = (j0 + 16 + l16 <= qg) ? __expf(fminf(s1[r] * 0.125f, 30.f)) : 0.f;
                    }
                } else {
#pragma unroll
                    for (int r = 0; r < 4; ++r) {
                        p0[r] = __expf(fminf(s0[r] * 0.125f, 30.f));
                        p1[r] = __expf(fminf(s1[r] * 0.125f, 30.f));
                    }
                }
#pragma unroll
                for (int r = 0; r < 4; ++r) {
                    ls[g][r] += p0[r] + p1[r];
                    int row = quad * 4 + r;
                    Pw[g * 640 + row * 40 + ((((l16 >> 3) + 0) ^ quad) << 3) + (l16 & 7)] = f2bf_fast(p0[r]);
                    Pw[g * 640 + row * 40 + ((((l16 >> 3) + 2) ^ quad) << 3) + (l16 & 7)] = f2bf_fast(p1[r]);
                }
                bf16x8 ap = ld8(&Pw[g * 640 + prd]);
                __builtin_amdgcn_s_setprio(1);
                o[g][0] = __builtin_amdgcn_mfma_f32_16x16x32_bf16(ap, vf[0], o[g][0], 0, 0, 0);
                o[g][1] = __builtin_amdgcn_mfma_f32_16x16x32_bf16(ap, vf[1], o[g][1], 0, 0, 0);
                o[g][2] = __builtin_amdgcn_mfma_f32_16x16x32_bf16(ap, vf[2], o[g][2], 0, 0, 0);
                o[g][3] = __builtin_amdgcn_mfma_f32_16x16x32_bf16(ap, vf[3], o[g][3], 0, 0, 0);
                __builtin_amdgcn_s_setprio(0);
            }
        }
    };

    // pipeline: NT >= 4 always; 2 tiles in flight, vmcnt(2) steady state
    STAGE(0, 0);
    STAGE(1, 32);
#pragma unroll 1
    for (int it = 0; it < NT - 2; ++it) {
        asm volatile("s_waitcnt vmcnt(2)" ::: "memory");
        __builtin_amdgcn_s_barrier();
        __builtin_amdgcn_sched_barrier(0);
        TILE(it & 1, it * 32);
        __builtin_amdgcn_s_barrier();
        STAGE(it & 1, (it + 2) * 32);
    }
    asm volatile("s_waitcnt vmcnt(2)" ::: "memory");
    __builtin_amdgcn_s_barrier();
    __builtin_amdgcn_sched_barrier(0);
    TILE(NT & 1, (NT - 2) * 32);
    asm volatile("s_waitcnt vmcnt(0)" ::: "memory");
    __builtin_amdgcn_s_barrier();
    __builtin_amdgcn_sched_barrier(0);
    TILE((NT - 1) & 1, (NT - 1) * 32);

    // epilogue: wave-local normalize + store (each wave owns its q rows end-to-end)
#pragma unroll
    for (int g = 0; g < 2; ++g) {
        const int G = g ? G1 : G0;
#pragma unroll
        for (int r = 0; r < 4; ++r) {
            float v = ls[g][r];
            v += __shfl_xor(v, 1); v += __shfl_xor(v, 2);
            v += __shfl_xor(v, 4); v += __shfl_xor(v, 8);
            float inv = 1.0f / v;
            int qrow = G + quad * 4 + r;
            U16* op = Og + (size_t)(b * 2048 + qrow) * 1024 + h * 64 + l16;
#pragma unroll
            for (int dg = 0; dg < 4; ++dg)
                op[dg * 16] = f2bf(o[g][dg][r] * inv);
        }
    }
}

// ---------------- sliding-window cross attention (9 kv per query)
__global__ __launch_bounds__(256) void cross_attn(const U16* __restrict__ qc, const U16* __restrict__ kvc,
                                                  const int* __restrict__ seg_ids, U16* __restrict__ oc) {
    const int tok = blockIdx.x;
    const int b = tok >> 11;
    const int w = threadIdx.x >> 6, lane = threadIdx.x & 63;
    const int h = blockIdx.y * 4 + w;
    const int seg = seg_ids[tok];
    const size_t qoff = (size_t)tok * 1024 + h * 64 + lane;
    float q = bf2f(qc[qoff]);
    float s[9];
#pragma unroll
    for (int jj = 0; jj < 9; jj++) {
        int j = seg - 8 + jj;
        float sc = -INFINITY;
        if (j >= 0) {
            float kv = bf2f(kvc[((size_t)(b * 512) + j) * 2048 + h * 64 + lane]);
            sc = q * kv;
            sc += __shfl_xor(sc, 1); sc += __shfl_xor(sc, 2); sc += __shfl_xor(sc, 4);
            sc += __shfl_xor(sc, 8); sc += __shfl_xor(sc, 16); sc += __shfl_xor(sc, 32);
            sc *= 0.125f;
        }
        s[jj] = sc;
    }
    float m = s[0];
#pragma unroll
    for (int jj = 1; jj < 9; jj++) m = fmaxf(m, s[jj]);
    float l = 0.f, o = 0.f;
#pragma unroll
    for (int jj = 0; jj < 9; jj++) {
        int j = seg - 8 + jj;
        if (j >= 0) {
            float p = __expf(s[jj] - m);
            l += p;
            o += p * bf2f(kvc[((size_t)(b * 512) + j) * 2048 + 1024 + h * 64 + lane]);
        }
    }
    oc[qoff] = f2bf(o / l);
}

extern "C" void kernel_launch(void* const* d_in, const int* in_sizes, int n_in,
                              void* d_out, int out_size, void* d_ws, size_t ws_size,
                              hipStream_t stream) {
    const float* x      = (const float*)d_in[0];
    const float* memory = (const float*)d_in[1];
    const int*   seg    = (const int*)d_in[2];
    const float* n1w    = (const float*)d_in[3];
    const float* W_dq   = (const float*)d_in[4];
    const float* W_uq   = (const float*)d_in[5];
    const float* W_dkv  = (const float*)d_in[6];
    const float* W_uk   = (const float*)d_in[7];
    const float* W_uv   = (const float*)d_in[8];
    const float* W_os   = (const float*)d_in[9];
    const float* n2w    = (const float*)d_in[10];
    const float* W_qc   = (const float*)d_in[11];
    const float* W_kc   = (const float*)d_in[12];
    const float* W_vc   = (const float*)d_in[13];
    const float* W_oc   = (const float*)d_in[14];
    const float* n3w    = (const float*)d_in[15];
    const float* W_gate = (const float*)d_in[16];
    const float* W_up   = (const float*)d_in[17];
    const float* W_down = (const float*)d_in[18];
    (void)in_sizes; (void)n_in; (void)out_size; (void)ws_size;

    char* ws = (char*)d_ws;
    size_t off = 0;
    auto alloc = [&](size_t bytes) -> void* {
        void* p = ws + off;
        off += (bytes + 255) & ~(size_t)255;
        return p;
    };
    const size_t MB = 1024 * 1024;
    U16* hbuf     = (U16*)alloc(8 * MB);
    float* x1     = (float*)alloc(16 * MB);
    float* x2     = (float*)alloc(16 * MB);
    float* cq32   = (float*)alloc(8 * MB);          // 4 split-K fp32 partials [4][4096*128]
    U16* Wt_dqkv  = (U16*)alloc(128 * 1024 * 2);
    U16* Wt_uqk   = (U16*)alloc(2048 * 128 * 2);
    U16* Wt_uv    = (U16*)alloc(1024 * 128 * 2);
    U16* Wt_os    = (U16*)alloc(1024 * 1024 * 2);
    U16* Wt_qc    = (U16*)alloc(1024 * 1024 * 2);
    U16* Wt_kvc   = (U16*)alloc((size_t)2048 * 1024 * 2);
    U16* Wt_oc    = (U16*)alloc(1024 * 1024 * 2);
    U16* Wt_gu    = (U16*)alloc((size_t)8192 * 1024 * 2);
    U16* Wt_down  = (U16*)alloc((size_t)1024 * 4096 * 2);
    U16* mem_bf   = (U16*)alloc(1024 * 1024 * 2);
    char* arena   = ws + off;
    // phase 1
    U16* cq  = (U16*)(arena);                  // [4096][128]
    U16* qkb = (U16*)(arena + 1 * MB);         // [4096][2048]
    U16* vt  = (U16*)(arena + 17 * MB);        // [1024][4096]
    U16* ob  = (U16*)(arena + 25 * MB);        // [4096][1024]
    // phase 2
    U16* qcb  = (U16*)(arena);                 // [4096][1024]
    U16* kvcb = (U16*)(arena + 8 * MB);        // [1024][2048]
    U16* ocb  = (U16*)(arena + 12 * MB);       // [4096][1024]
    // phase 3
    U16* gact = (U16*)(arena);                 // [4096][4096]

    // ---- merged weight prep
    WTable T;
    int i = 0;
    auto ent = [&](const float* s, U16* d, int K, int N, int Kpad, int Npad, int koff, int noff) {
        T.e[i++] = WEnt{s, d, K, N, Kpad, Npad, koff, noff, (Kpad >> 5) * (Npad >> 5)};
    };
    ent(W_dq,   Wt_dqkv, 1024, 32,   1024, 32,   0,  0);
    ent(W_dkv,  Wt_dqkv, 1024, 64,   1024, 96,   0,  32);
    ent(W_uq,   Wt_uqk,  32,   1024, 128,  1024, 0,  0);
    ent(W_uk,   Wt_uqk,  64,   1024, 128,  1024, 32, 1024);
    ent(W_uv,   Wt_uv,   64,   1024, 128,  1024, 32, 0);
    ent(W_os,   Wt_os,   1024, 1024, 1024, 1024, 0,  0);
    ent(W_qc,   Wt_qc,   1024, 1024, 1024, 1024, 0,  0);
    ent(W_kc,   Wt_kvc,  1024, 1024, 1024, 1024, 0,  0);
    ent(W_vc,   Wt_kvc,  1024, 1024, 1024, 1024, 0,  1024);
    ent(W_oc,   Wt_oc,   1024, 1024, 1024, 1024, 0,  0);
    ent(W_gate, Wt_gu,   1024, 4096, 1024, 4096, 0,  0);
    ent(W_up,   Wt_gu,   1024, 4096, 1024, 4096, 0,  4096);
    ent(W_down, Wt_down, 4096, 1024, 4096, 1024, 0,  0);
    int total_tiles = 0;
    for (int j = 0; j < 13; j++) total_tiles += T.e[j].tiles;
    wtrans_all<<<total_tiles, 256, 0, stream>>>(T);
    f2bf_k<<<1024, 256, 0, stream>>>(memory, mem_bf, 1024 * 1024);

    // ---- phase 1: self-attention block
    rmsnorm_k<<<4096, 256, 0, stream>>>(x, n1w, hbuf);
    gemm_m64<5><<<dim3(1, 64, 4), 256, 0, stream>>>(hbuf, Wt_dqkv, cq32, nullptr, 4096, 128, 256, 1024, 1024, 128);
    cq_reduce<<<512, 256, 0, stream>>>(cq32, cq);
    qkuv_gemm<<<dim3(24, 32), 256, 0, stream>>>(cq, Wt_uqk, Wt_uv, qkb, vt);
    flash_self4<<<512, 256, 0, stream>>>(qkb, vt, ob);
    gemm_m64<1><<<dim3(8, 64), 256, 0, stream>>>(ob, Wt_os, x1, x, 4096, 1024, 1024, 1024, 1024, 1024);

    // ---- phase 2: cross attention block
    rmsnorm_k<<<4096, 256, 0, stream>>>(x1, n2w, hbuf);
    qckv_gemm<<<768, 256, 0, stream>>>(hbuf, Wt_qc, mem_bf, Wt_kvc, qcb, kvcb);
    cross_attn<<<dim3(4096, 4), 256, 0, stream>>>(qcb, kvcb, seg, ocb);
    gemm_m64<1><<<dim3(8, 64), 256, 0, stream>>>(ocb, Wt_oc, x2, x1, 4096, 1024, 1024, 1024, 1024, 1024);

    // ---- phase 3: FFN (fused gate+up+silu 256x256 pipelined, then down)
    rmsnorm_k<<<4096, 256, 0, stream>>>(x2, n3w, hbuf);
    ffn1_8ph<<<dim3(32, 16), 512, 0, stream>>>(hbuf, Wt_gu, gact);
    gemm_m64<1><<<dim3(8, 64), 256, 0, stream>>>(gact, Wt_down, (float*)d_out, x2, 4096, 1024, 4096, 4096, 4096, 1024);
}

// Round 6
// 499.619 us; speedup vs baseline: 1.0137x; 1.0137x over previous
//
#include <hip/hip_runtime.h>
#include <stdint.h>

typedef unsigned short U16;
typedef __bf16 bf16x8 __attribute__((ext_vector_type(8)));
typedef unsigned short us8 __attribute__((ext_vector_type(8)));
typedef float f32x4 __attribute__((ext_vector_type(4)));

__device__ __forceinline__ U16 f2bf(float f) {
    unsigned u = __builtin_bit_cast(unsigned, f);
    unsigned r = (u + 0x7fff + ((u >> 16) & 1)) >> 16;
    return (U16)r;
}
__device__ __forceinline__ U16 f2bf_fast(float f) {   // round-half-up, for positive non-NaN
    return (U16)((__builtin_bit_cast(unsigned, f) + 0x8000u) >> 16);
}
__device__ __forceinline__ float bf2f(U16 v) {
    return __builtin_bit_cast(float, (unsigned)v << 16);
}
__device__ __forceinline__ bf16x8 ld8(const U16* p) { return __builtin_bit_cast(bf16x8, *(const us8*)p); }

// async global->LDS, 16B per lane; lds base wave-uniform, HW scatters lane i at base+i*16
__device__ __forceinline__ void async16(const U16* g, U16* l) {
    auto* gp = (const __attribute__((address_space(1))) U16*)g;
    auto* lp = (__attribute__((address_space(3))) U16*)(uintptr_t)(uint32_t)(uintptr_t)l;
    __builtin_amdgcn_global_load_lds(gp, lp, 16, 0, 0);
}

// ---------------- merged weight transpose: dst[noff+n][kk] = bf16(src[kk-koff][n]), zero-padded
struct WEnt { const float* src; U16* dst; int K, N, Kpad, Npad, koff, noff, tiles; };
struct WTable { WEnt e[13]; };

__global__ __launch_bounds__(256) void wtrans_all(WTable t) {
    int bx = blockIdx.x, ei = 0;
    while (bx >= t.e[ei].tiles) { bx -= t.e[ei].tiles; ei++; }
    const WEnt E = t.e[ei];
    const int ntn = E.Npad >> 5;
    const int n0 = (bx % ntn) * 32, k0 = (bx / ntn) * 32;
    __shared__ float tile[32][33];
    const int tx = threadIdx.x & 31, ty = threadIdx.x >> 5;
#pragma unroll
    for (int i = 0; i < 4; i++) {
        int kk = k0 + ty + i * 8, n = n0 + tx;
        int k = kk - E.koff;
        float v = (k >= 0 && k < E.K && n < E.N) ? E.src[(size_t)k * E.N + n] : 0.f;
        tile[ty + i * 8][tx] = v;
    }
    __syncthreads();
#pragma unroll
    for (int i = 0; i < 4; i++) {
        int n = n0 + ty + i * 8, kk = k0 + tx;
        E.dst[(size_t)(E.noff + n) * E.Kpad + kk] = f2bf(tile[tx][ty + i * 8]);
    }
}

// ---------------- fp32 -> bf16 convert
__global__ __launch_bounds__(256) void f2bf_k(const float* __restrict__ in, U16* __restrict__ out, int n) {
    int i = (blockIdx.x * 256 + threadIdx.x) * 4;
    if (i < n) {
        float4 v = *(const float4*)(in + i);
        out[i + 0] = f2bf(v.x); out[i + 1] = f2bf(v.y);
        out[i + 2] = f2bf(v.z); out[i + 3] = f2bf(v.w);
    }
}

// ---------------- reduce 4 fp32 partials [4][4096*128] -> bf16
__global__ __launch_bounds__(256) void cq_reduce(const float* __restrict__ p, U16* __restrict__ out) {
    int i = (blockIdx.x * 256 + threadIdx.x) * 4;
    const float4 a = *(const float4*)(p + i);
    const float4 b = *(const float4*)(p + 524288 + i);
    const float4 c = *(const float4*)(p + 2 * 524288 + i);
    const float4 d = *(const float4*)(p + 3 * 524288 + i);
    out[i + 0] = f2bf(a.x + b.x + c.x + d.x);
    out[i + 1] = f2bf(a.y + b.y + c.y + d.y);
    out[i + 2] = f2bf(a.z + b.z + c.z + d.z);
    out[i + 3] = f2bf(a.w + b.w + c.w + d.w);
}

// ---------------- RMSNorm: fp32 row (1024) -> bf16
__global__ __launch_bounds__(256) void rmsnorm_k(const float* __restrict__ x, const float* __restrict__ w,
                                                 U16* __restrict__ h) {
    const int row = blockIdx.x, tid = threadIdx.x;
    const float4 v = *(const float4*)(x + (size_t)row * 1024 + tid * 4);
    float ss = v.x * v.x + v.y * v.y + v.z * v.z + v.w * v.w;
#pragma unroll
    for (int o = 32; o > 0; o >>= 1) ss += __shfl_xor(ss, o);
    __shared__ float red[4];
    if ((tid & 63) == 0) red[tid >> 6] = ss;
    __syncthreads();
    float tot = red[0] + red[1] + red[2] + red[3];
    float sc = rsqrtf(tot * (1.0f / 1024.0f) + 1e-6f);
    const float4 wv = *(const float4*)(w + tid * 4);
    U16* hp = h + (size_t)row * 1024 + tid * 4;
    hp[0] = f2bf(v.x * sc * wv.x); hp[1] = f2bf(v.y * sc * wv.y);
    hp[2] = f2bf(v.z * sc * wv.z); hp[3] = f2bf(v.w * sc * wv.w);
}

// ---------------- merged uq/uk + uv GEMM from cq [4096][128], K=128
// grid (24, 32): x<16 -> qkb bf16 [4096][2048]; x>=16 -> vt transposed bf16 [1024][4096]
__global__ __launch_bounds__(256) void qkuv_gemm(const U16* __restrict__ A, const U16* __restrict__ Wuqk,
                                                 const U16* __restrict__ Wuv,
                                                 U16* __restrict__ qkb, U16* __restrict__ vt) {
    __shared__ __align__(16) U16 As[2][128 * 32];
    __shared__ __align__(16) U16 Bs[2][128 * 32];
    __shared__ __align__(16) U16 Ts[4][64 * 80];
    const int tid = threadIdx.x;
    const bool isuv = blockIdx.x >= 16;
    const U16* Bt = isuv ? Wuv : Wuqk;
    const int n0 = (isuv ? blockIdx.x - 16 : blockIdx.x) * 128;
    const int m0 = blockIdx.y * 128;
    const int wave = tid >> 6, lane = tid & 63, l16 = lane & 15, quad = lane >> 4;
    const int wm = (wave >> 1) * 64, wn = (wave & 1) * 64;
    const int sr = lane >> 2, sc = (lane & 3) * 8;
    const U16* gA = A + (size_t)(m0 + wave * 32 + sr) * 128 + sc;
    const U16* gB = Bt + (size_t)(n0 + wave * 32 + sr) * 128 + sc;
    f32x4 acc[4][4] = {};
    for (int kt = 0; kt < 128; kt += 64) {
        __syncthreads();
#pragma unroll
        for (int p = 0; p < 2; p++) {
            const int o = kt + p * 32;
            async16(gA + o, &As[p][(wave * 32) * 32]);
            async16(gA + 16 * 128 + o, &As[p][(wave * 32 + 16) * 32]);
            async16(gB + o, &Bs[p][(wave * 32) * 32]);
            async16(gB + 16 * 128 + o, &Bs[p][(wave * 32 + 16) * 32]);
        }
        __syncthreads();
#pragma unroll
        for (int p = 0; p < 2; p++) {
            bf16x8 af[4], bfr[4];
#pragma unroll
            for (int i = 0; i < 4; i++) {
                af[i]  = ld8(&As[p][(wm + i * 16 + l16) * 32 + quad * 8]);
                bfr[i] = ld8(&Bs[p][(wn + i * 16 + l16) * 32 + quad * 8]);
            }
#pragma unroll
            for (int mi = 0; mi < 4; mi++)
#pragma unroll
                for (int ni = 0; ni < 4; ni++)
                    acc[mi][ni] = __builtin_amdgcn_mfma_f32_16x16x32_bf16(af[mi], bfr[ni], acc[mi][ni], 0, 0, 0);
        }
    }
    if (isuv) {
        // per-wave LDS transpose -> coalesced 16B stores along m into vt [1024][4096]
        U16* T = Ts[wave];
#pragma unroll
        for (int mi = 0; mi < 4; mi++)
#pragma unroll
            for (int ni = 0; ni < 4; ni++)
#pragma unroll
                for (int r = 0; r < 4; r++)
                    T[(ni * 16 + l16) * 80 + mi * 16 + quad * 4 + r] = f2bf(acc[mi][ni][r]);
#pragma unroll
        for (int c = 0; c < 8; c++) {
            int nloc = (lane >> 3) + 8 * c, mloc = (lane & 7) * 8;
            us8 v = *(const us8*)&T[nloc * 80 + mloc];
            *(us8*)&vt[(size_t)(n0 + wn + nloc) * 4096 + (m0 + wm + mloc)] = v;
        }
    } else {
#pragma unroll
        for (int mi = 0; mi < 4; mi++)
#pragma unroll
            for (int r = 0; r < 4; r++) {
                int m = m0 + wm + mi * 16 + quad * 4 + r;
#pragma unroll
                for (int ni = 0; ni < 4; ni++)
                    qkb[(size_t)m * 2048 + n0 + wn + ni * 16 + l16] = f2bf(acc[mi][ni][r]);
            }
    }
}

// ---------------- 64x128 GEMM, double-buffered BK=64, counted vmcnt (ffn1-R1 recipe)
// EPI 0: bf16. EPI 1: fp32 = resid + acc. EPI 5: fp32 partial at Cout + z*524288 (no resid).
template <int EPI>
__global__ __launch_bounds__(256) void gemm_m64(const U16* __restrict__ A, const U16* __restrict__ Bt,
                                                void* __restrict__ Cout, const float* __restrict__ resid,
                                                int M, int N, int K, int lda, int ldb, int ldc) {
    __shared__ __align__(16) U16 As[2][2][64 * 32];   // [buf][panel]
    __shared__ __align__(16) U16 Bs[2][2][128 * 32];
    const int tid = threadIdx.x;
    const int m0 = blockIdx.y * 64, n0 = blockIdx.x * 128;
    const int k0 = blockIdx.z * K;
    const int wave = tid >> 6, lane = tid & 63, l16 = lane & 15, quad = lane >> 4;
    const int wm = (wave >> 1) * 32, wn = (wave & 1) * 64;
    const int sr = lane >> 2, sc = (lane & 3) * 8;
    const U16* gA = A + (size_t)(m0 + wave * 16 + sr) * lda + sc + k0;
    const U16* gB = Bt + (size_t)(n0 + wave * 32 + sr) * ldb + sc + k0;

    auto STAGE = [&](int buf, int kt) {   // 6 global_load_lds per wave
#pragma unroll
        for (int p = 0; p < 2; p++) {
            const int o = kt + p * 32;
            async16(gA + o, &As[buf][p][(wave * 16) * 32]);
            async16(gB + o, &Bs[buf][p][(wave * 32) * 32]);
            async16(gB + (size_t)16 * ldb + o, &Bs[buf][p][(wave * 32 + 16) * 32]);
        }
    };

    f32x4 acc[2][4] = {};
    const int NTK = K >> 6;               // 64-wide K tiles (K multiple of 128 everywhere -> NTK >= 2)
    STAGE(0, 0);
    STAGE(1, 64);
#pragma unroll 1
    for (int t = 0; t < NTK; ++t) {
        if (t == NTK - 1) asm volatile("s_waitcnt vmcnt(0)" ::: "memory");
        else              asm volatile("s_waitcnt vmcnt(6)" ::: "memory");
        __builtin_amdgcn_s_barrier();
        __builtin_amdgcn_sched_barrier(0);
        const int buf = t & 1;
#pragma unroll
        for (int p = 0; p < 2; p++) {
            bf16x8 af[2], bfr[4];
#pragma unroll
            for (int i = 0; i < 2; i++)
                af[i] = ld8(&As[buf][p][(wm + i * 16 + l16) * 32 + quad * 8]);
#pragma unroll
            for (int i = 0; i < 4; i++)
                bfr[i] = ld8(&Bs[buf][p][(wn + i * 16 + l16) * 32 + quad * 8]);
#pragma unroll
            for (int mi = 0; mi < 2; mi++)
#pragma unroll
                for (int ni = 0; ni < 4; ni++)
                    acc[mi][ni] = __builtin_amdgcn_mfma_f32_16x16x32_bf16(af[mi], bfr[ni], acc[mi][ni], 0, 0, 0);
        }
        __builtin_amdgcn_s_barrier();     // all waves done reading buf (lgkm-waited before MFMA use)
        if (t + 2 < NTK) STAGE(buf, (t + 2) * 64);
    }
#pragma unroll
    for (int mi = 0; mi < 2; mi++) {
#pragma unroll
        for (int r = 0; r < 4; r++) {
            int m = m0 + wm + mi * 16 + quad * 4 + r;
#pragma unroll
            for (int ni = 0; ni < 4; ni++) {
                int n = n0 + wn + ni * 16 + l16;
                float val = acc[mi][ni][r];
                if (EPI == 0) ((U16*)Cout)[(size_t)m * ldc + n] = f2bf(val);
                else if (EPI == 1) ((float*)Cout)[(size_t)m * ldc + n] = resid[(size_t)m * ldc + n] + val;
                else if (EPI == 5) ((float*)Cout)[(size_t)blockIdx.z * 524288 + (size_t)m * ldc + n] = val;
            }
        }
    }
}

// ---------------- merged qc + kvc GEMM, double-buffered BK=64 (same recipe; K=1024, lda=ldb=1024)
// 768 blocks: [0,512) -> qcb [4096][1024]; [512,768) -> kvcb [1024][2048]
__global__ __launch_bounds__(256) void qckv_gemm(const U16* __restrict__ hbuf, const U16* __restrict__ Wqc,
                                                 const U16* __restrict__ memb, const U16* __restrict__ Wkvc,
                                                 U16* __restrict__ qcb, U16* __restrict__ kvcb) {
    __shared__ __align__(16) U16 As[2][2][64 * 32];
    __shared__ __align__(16) U16 Bs[2][2][128 * 32];
    const int tid = threadIdx.x, bid = blockIdx.x;
    const U16 *A, *Bt; U16* C; int m0, n0, ldc;
    if (bid < 512) { A = hbuf; Bt = Wqc;  C = qcb;  m0 = (bid >> 3) * 64; n0 = (bid & 7) * 128;  ldc = 1024; }
    else { int b2 = bid - 512; A = memb; Bt = Wkvc; C = kvcb; m0 = (b2 >> 4) * 64; n0 = (b2 & 15) * 128; ldc = 2048; }
    const int wave = tid >> 6, lane = tid & 63, l16 = lane & 15, quad = lane >> 4;
    const int wm = (wave >> 1) * 32, wn = (wave & 1) * 64;
    const int sr = lane >> 2, sc = (lane & 3) * 8;
    const U16* gA = A + (size_t)(m0 + wave * 16 + sr) * 1024 + sc;
    const U16* gB = Bt + (size_t)(n0 + wave * 32 + sr) * 1024 + sc;

    auto STAGE = [&](int buf, int kt) {
#pragma unroll
        for (int p = 0; p < 2; p++) {
            const int o = kt + p * 32;
            async16(gA + o, &As[buf][p][(wave * 16) * 32]);
            async16(gB + o, &Bs[buf][p][(wave * 32) * 32]);
            async16(gB + 16 * 1024 + o, &Bs[buf][p][(wave * 32 + 16) * 32]);
        }
    };

    f32x4 acc[2][4] = {};
    STAGE(0, 0);
    STAGE(1, 64);
#pragma unroll 1
    for (int t = 0; t < 16; ++t) {
        if (t == 15) asm volatile("s_waitcnt vmcnt(0)" ::: "memory");
        else         asm volatile("s_waitcnt vmcnt(6)" ::: "memory");
        __builtin_amdgcn_s_barrier();
        __builtin_amdgcn_sched_barrier(0);
        const int buf = t & 1;
#pragma unroll
        for (int p = 0; p < 2; p++) {
            bf16x8 af[2], bfr[4];
#pragma unroll
            for (int i = 0; i < 2; i++)
                af[i] = ld8(&As[buf][p][(wm + i * 16 + l16) * 32 + quad * 8]);
#pragma unroll
            for (int i = 0; i < 4; i++)
                bfr[i] = ld8(&Bs[buf][p][(wn + i * 16 + l16) * 32 + quad * 8]);
#pragma unroll
            for (int mi = 0; mi < 2; mi++)
#pragma unroll
                for (int ni = 0; ni < 4; ni++)
                    acc[mi][ni] = __builtin_amdgcn_mfma_f32_16x16x32_bf16(af[mi], bfr[ni], acc[mi][ni], 0, 0, 0);
        }
        __builtin_amdgcn_s_barrier();
        if (t + 2 < 16) STAGE(buf, (t + 2) * 64);
    }
#pragma unroll
    for (int mi = 0; mi < 2; mi++)
#pragma unroll
        for (int r = 0; r < 4; r++) {
            int m = m0 + wm + mi * 16 + quad * 4 + r;
#pragma unroll
            for (int ni = 0; ni < 4; ni++)
                C[(size_t)m * ldc + n0 + wn + ni * 16 + l16] = f2bf(acc[mi][ni][r]);
        }
}

// ---------------- fused FFN1, 256x256 deep-pipelined (T2 swizzle + T3/T4 counted vmcnt + T5 setprio)
// Round-4 coarse-TILE schedule (73.5 us) — per-phase barriers regressed (R5), reverted.
__global__ __launch_bounds__(512, 2) void ffn1_8ph(const U16* __restrict__ A, const U16* __restrict__ Wgu,
                                                   U16* __restrict__ Cout) {
    __shared__ __align__(16) U16 As[2][256 * 64];
    __shared__ __align__(16) U16 Bs[2][256 * 64];
    const int tid = threadIdx.x;
    const int wid = tid >> 6, lane = tid & 63;
    const int l16 = lane & 15, quad = lane >> 4;
    const int n0 = blockIdx.x * 128;          // output col tile
    const int m0 = blockIdx.y * 256;          // row tile
    const int wr = wid >> 2, wc = wid & 3;
    const int wm = wr * 128;                  // wave m offset in tile
    const int wn = wc * 64;                   // wave B-row offset in tile
    const int srow = lane >> 3;               // 0..7
    const int schunk = (lane & 7) ^ srow;     // inverse-swizzled source chunk
    const U16* gA = A + (size_t)(m0 + wid * 32 + srow) * 1024 + schunk * 8;
    const U16* gB = Wgu + (size_t)((wid & 1) * 4096 + n0 + (wid >> 1) * 32 + srow) * 1024 + schunk * 8;

    auto STAGE = [&](int buf, int kt) {       // 8 global_load_lds per wave
        U16* la = &As[buf][(wid * 32) * 64];
        U16* lb = &Bs[buf][(wid * 32) * 64];
        const U16* pa = gA + kt;
        const U16* pb = gB + kt;
#pragma unroll
        for (int j = 0; j < 4; ++j) {
            async16(pa + j * 8 * 1024, la + j * 8 * 64);
            async16(pb + j * 8 * 1024, lb + j * 8 * 64);
        }
    };

    f32x4 acc[8][4] = {};                     // [mi][ni]; ni 0,1 = gate frags, 2,3 = up frags

    auto TILE = [&](int buf) {
        const U16* Ab = &As[buf][0];
        const U16* Bb = &Bs[buf][0];
        const int cx = l16 & 7;               // read-side swizzle XOR
        bf16x8 a0[4][2], a1[4][2], b0[2][2], b1[2][2];
#pragma unroll
        for (int mi = 0; mi < 4; ++mi)
#pragma unroll
            for (int kh = 0; kh < 2; ++kh)
                a0[mi][kh] = ld8(&Ab[(wm + mi * 16 + l16) * 64 + (((kh * 4 + quad) ^ cx) << 3)]);
#pragma unroll
        for (int ni = 0; ni < 2; ++ni)
#pragma unroll
            for (int kh = 0; kh < 2; ++kh)
                b0[ni][kh] = ld8(&Bb[(wn + ni * 16 + l16) * 64 + (((kh * 4 + quad) ^ cx) << 3)]);
#pragma unroll
        for (int ni = 0; ni < 2; ++ni)
#pragma unroll
            for (int kh = 0; kh < 2; ++kh)
                b1[ni][kh] = ld8(&Bb[(wn + 32 + ni * 16 + l16) * 64 + (((kh * 4 + quad) ^ cx) << 3)]);
        __builtin_amdgcn_s_setprio(1);
#pragma unroll
        for (int mi = 0; mi < 4; ++mi)
#pragma unroll
            for (int ni = 0; ni < 2; ++ni)
#pragma unroll
                for (int kh = 0; kh < 2; ++kh)
                    acc[mi][ni] = __builtin_amdgcn_mfma_f32_16x16x32_bf16(a0[mi][kh], b0[ni][kh], acc[mi][ni], 0, 0, 0);
        __builtin_amdgcn_s_setprio(0);
#pragma unroll
        for (int mi = 0; mi < 4; ++mi)
#pragma unroll
            for (int kh = 0; kh < 2; ++kh)
                a1[mi][kh] = ld8(&Ab[(wm + 64 + mi * 16 + l16) * 64 + (((kh * 4 + quad) ^ cx) << 3)]);
        __builtin_amdgcn_s_setprio(1);
#pragma unroll
        for (int mi = 0; mi < 4; ++mi)
#pragma unroll
            for (int ni = 0; ni < 2; ++ni)
#pragma unroll
                for (int kh = 0; kh < 2; ++kh)
                    acc[mi][2 + ni] = __builtin_amdgcn_mfma_f32_16x16x32_bf16(a0[mi][kh], b1[ni][kh], acc[mi][2 + ni], 0, 0, 0);
        __builtin_amdgcn_s_setprio(0);
        __builtin_amdgcn_s_setprio(1);
#pragma unroll
        for (int mi = 0; mi < 4; ++mi)
#pragma unroll
            for (int ni = 0; ni < 2; ++ni)
#pragma unroll
                for (int kh = 0; kh < 2; ++kh)
                    acc[4 + mi][2 + ni] = __builtin_amdgcn_mfma_f32_16x16x32_bf16(a1[mi][kh], b1[ni][kh], acc[4 + mi][2 + ni], 0, 0, 0);
        __builtin_amdgcn_s_setprio(0);
        __builtin_amdgcn_s_setprio(1);
#pragma unroll
        for (int mi = 0; mi < 4; ++mi)
#pragma unroll
            for (int ni = 0; ni < 2; ++ni)
#pragma unroll
                for (int kh = 0; kh < 2; ++kh)
                    acc[4 + mi][ni] = __builtin_amdgcn_mfma_f32_16x16x32_bf16(a1[mi][kh], b0[ni][kh], acc[4 + mi][ni], 0, 0, 0);
        __builtin_amdgcn_s_setprio(0);
    };

    STAGE(0, 0);
    STAGE(1, 64);
#pragma unroll 1
    for (int t2 = 0; t2 < 7; ++t2) {
        asm volatile("s_waitcnt vmcnt(8)" ::: "memory");
        __builtin_amdgcn_s_barrier();
        __builtin_amdgcn_sched_barrier(0);
        TILE(0);
        __builtin_amdgcn_s_barrier();
        STAGE(0, (2 * t2 + 2) * 64);
        asm volatile("s_waitcnt vmcnt(8)" ::: "memory");
        __builtin_amdgcn_s_barrier();
        __builtin_amdgcn_sched_barrier(0);
        TILE(1);
        __builtin_amdgcn_s_barrier();
        STAGE(1, (2 * t2 + 3) * 64);
    }
    asm volatile("s_waitcnt vmcnt(8)" ::: "memory");
    __builtin_amdgcn_s_barrier();
    __builtin_amdgcn_sched_barrier(0);
    TILE(0);
    asm volatile("s_waitcnt vmcnt(0)" ::: "memory");
    __builtin_amdgcn_s_barrier();
    __builtin_amdgcn_sched_barrier(0);
    TILE(1);

#pragma unroll
    for (int mi = 0; mi < 8; ++mi)
#pragma unroll
        for (int r = 0; r < 4; ++r) {
            int m = m0 + wm + mi * 16 + quad * 4 + r;
#pragma unroll
            for (int ni = 0; ni < 2; ++ni) {
                int col = n0 + wc * 32 + ni * 16 + l16;
                float g = acc[mi][ni][r], u = acc[mi][ni + 2][r];
                float act = g / (1.f + __expf(-g)) * u;
                Cout[(size_t)m * 4096 + col] = f2bf(act);
            }
        }
}

// ---------------- flash self-attention v4: LDS-staged K/V, double-buffered, counted vmcnt
// Block = 128 q rows (grid 512 = 16 Tq x 32 bh, T descending). 4 waves; wave w owns q-row
// groups {q0 + w*16, q0 + 64 + w*16}. j-tiles of 32 staged cooperatively:
//   K tile [32][64] bf16 (chunk ^= row&7 swizzle), V tile [64][32] bf16 (chunk ^= (row&3)^((row>>2)&3)).
// global_load_lds dest is linear, so the swizzle is applied to the per-lane GLOBAL source
// (both-sides rule) and re-applied on the ds_read side.
__global__ __launch_bounds__(256, 3) void flash_self4(const U16* __restrict__ QK, const U16* __restrict__ Vt,
                                                      U16* __restrict__ Og) {
    __shared__ __align__(16) U16 Ks[2][32 * 64];
    __shared__ __align__(16) U16 Vs[2][64 * 32];
    __shared__ __align__(16) U16 Ps[4][1280];
    const int wave = threadIdx.x >> 6, lane = threadIdx.x & 63;
    const int l16 = lane & 15, quad = lane >> 4;
    const int bx = blockIdx.x;
    const int T = 15 - (bx >> 5);             // heavy tiles first
    const int bh = bx & 31, b = bh >> 4, h = bh & 15;
    const int q0 = T * 128;
    const int NT = 4 * T + 4;                 // number of 32-wide j-tiles
    const int G0 = q0 + wave * 16, G1 = q0 + 64 + wave * 16;
    // Q fragments (4 global loads, complete before first TILE via the vmcnt(2) below)
    bf16x8 aq[2][2];
    {
        const size_t r0 = (size_t)(b * 2048 + G0 + l16) * 2048 + h * 64;
        const size_t r1 = (size_t)(b * 2048 + G1 + l16) * 2048 + h * 64;
        aq[0][0] = ld8(QK + r0 + quad * 8); aq[0][1] = ld8(QK + r0 + 32 + quad * 8);
        aq[1][0] = ld8(QK + r1 + quad * 8); aq[1][1] = ld8(QK + r1 + 32 + quad * 8);
    }
    // staging source addresses (inverse-swizzled)
    const int krow = wave * 8 + (lane >> 3);                               // K tile row
    const int kchunk = (lane & 7) ^ (lane >> 3);                           // ^ (krow&7)
    const U16* gK = QK + (size_t)(b * 2048 + krow) * 2048 + 1024 + h * 64 + kchunk * 8;
    const int vrow = wave * 16 + (lane >> 2);                              // V tile row (d)
    const int vchunk = (lane & 3) ^ ((lane >> 2) & 3) ^ ((lane >> 4) & 3); // ^ (vr&3)^((vr>>2)&3)
    const U16* gV = Vt + (size_t)(h * 64 + vrow) * 4096 + b * 2048 + vchunk * 8;

    auto STAGE = [&](int buf, int j0) {       // 2 global_load_lds per wave
        async16(gK + (size_t)j0 * 2048, &Ks[buf][(wave * 8) * 64]);
        async16(gV + j0, &Vs[buf][(wave * 16) * 32]);
    };

    f32x4 o[2][4] = {};
    float ls[2][4] = {};
    U16* Pw = Ps[wave];
    const int prd = l16 * 40 + ((quad ^ (l16 >> 2)) << 3);

    auto TILE = [&](int buf, int j0) {
        // K fragments: row jh*16+l16, chunk (kh*4+quad)^(l16&7)
        bf16x8 kf[2][2];
#pragma unroll
        for (int jh = 0; jh < 2; ++jh)
#pragma unroll
            for (int kh = 0; kh < 2; ++kh)
                kf[jh][kh] = ld8(&Ks[buf][(jh * 16 + l16) * 64 + (((kh * 4 + quad) ^ (l16 & 7)) << 3)]);
        // V fragments: row dg*16+l16, chunk quad^(l16&3)^((l16>>2)&3)
        bf16x8 vf[4];
#pragma unroll
        for (int dg = 0; dg < 4; ++dg)
            vf[dg] = ld8(&Vs[buf][(dg * 16 + l16) * 32 + ((quad ^ (l16 & 3) ^ ((l16 >> 2) & 3)) << 3)]);
#pragma unroll
        for (int g = 0; g < 2; ++g) {
            const int G = g ? G1 : G0;
            if (j0 < G + 16) {                // group has unmasked rows in this tile
                f32x4 s0 = {}, s1 = {};
                __builtin_amdgcn_s_setprio(1);
                s0 = __builtin_amdgcn_mfma_f32_16x16x32_bf16(aq[g][0], kf[0][0], s0, 0, 0, 0);
                s0 = __builtin_amdgcn_mfma_f32_16x16x32_bf16(aq[g][1], kf[0][1], s0, 0, 0, 0);
                s1 = __builtin_amdgcn_mfma_f32_16x16x32_bf16(aq[g][0], kf[1][0], s1, 0, 0, 0);
                s1 = __builtin_amdgcn_mfma_f32_16x16x32_bf16(aq[g][1], kf[1][1], s1, 0, 0, 0);
                __builtin_amdgcn_s_setprio(0);
                float p0[4], p1[4];
                if (j0 + 32 > G) {            // diagonal tile: apply causal mask
#pragma unroll
                    for (int r = 0; r < 4; ++r) {
                        int qg = G + quad * 4 + r;
                        p0[r] = (j0 + l16 <= qg) ? __expf(fminf(s0[r] * 0.125f, 30.f)) : 0.f;
                        p1[r] = (j0 + 16 + l16 <= qg) ? __expf(fminf(s1[r] * 0.125f, 30.f)) : 0.f;
                    }
                } else {
#pragma unroll
                    for (int r = 0; r < 4; ++r) {
                        p0[r] = __expf(fminf(s0[r] * 0.125f, 30.f));
                        p1[r] = __expf(fminf(s1[r] * 0.125f, 30.f));
                    }
                }
#pragma unroll
                for (int r = 0; r < 4; ++r) {
                    ls[g][r] += p0[r] + p1[r];
                    int row = quad * 4 + r;
                    Pw[g * 640 + row * 40 + ((((l16 >> 3) + 0) ^ quad) << 3) + (l16 & 7)] = f2bf_fast(p0[r]);
                    Pw[g * 640 + row * 40 + ((((l16 >> 3) + 2) ^ quad) << 3) + (l16 & 7)] = f2bf_fast(p1[r]);
                }
                bf16x8 ap = ld8(&Pw[g * 640 + prd]);
                __builtin_amdgcn_s_setprio(1);
                o[g][0] = __builtin_amdgcn_mfma_f32_16x16x32_bf16(ap, vf[0], o[g][0], 0, 0, 0);
                o[g][1] = __builtin_amdgcn_mfma_f32_16x16x32_bf16(ap, vf[1], o[g][1], 0, 0, 0);
                o[g][2] = __builtin_amdgcn_mfma_f32_16x16x32_bf16(ap, vf[2], o[g][2], 0, 0, 0);
                o[g][3] = __builtin_amdgcn_mfma_f32_16x16x32_bf16(ap, vf[3], o[g][3], 0, 0, 0);
                __builtin_amdgcn_s_setprio(0);
            }
        }
    };

    // pipeline: NT >= 4 always; 2 tiles in flight, vmcnt(2) steady state
    STAGE(0, 0);
    STAGE(1, 32);
#pragma unroll 1
    for (int it = 0; it < NT - 2; ++it) {
        asm volatile("s_waitcnt vmcnt(2)" ::: "memory");
        __builtin_amdgcn_s_barrier();
        __builtin_amdgcn_sched_barrier(0);
        TILE(it & 1, it * 32);
        __builtin_amdgcn_s_barrier();
        STAGE(it & 1, (it + 2) * 32);
    }
    asm volatile("s_waitcnt vmcnt(2)" ::: "memory");
    __builtin_amdgcn_s_barrier();
    __builtin_amdgcn_sched_barrier(0);
    TILE(NT & 1, (NT - 2) * 32);
    asm volatile("s_waitcnt vmcnt(0)" ::: "memory");
    __builtin_amdgcn_s_barrier();
    __builtin_amdgcn_sched_barrier(0);
    TILE((NT - 1) & 1, (NT - 1) * 32);

    // epilogue: wave-local normalize + store (each wave owns its q rows end-to-end)
#pragma unroll
    for (int g = 0; g < 2; ++g) {
        const int G = g ? G1 : G0;
#pragma unroll
        for (int r = 0; r < 4; ++r) {
            float v = ls[g][r];
            v += __shfl_xor(v, 1); v += __shfl_xor(v, 2);
            v += __shfl_xor(v, 4); v += __shfl_xor(v, 8);
            float inv = 1.0f / v;
            int qrow = G + quad * 4 + r;
            U16* op = Og + (size_t)(b * 2048 + qrow) * 1024 + h * 64 + l16;
#pragma unroll
            for (int dg = 0; dg < 4; ++dg)
                op[dg * 16] = f2bf(o[g][dg][r] * inv);
        }
    }
}

// ---------------- sliding-window cross attention (9 kv per query)
__global__ __launch_bounds__(256) void cross_attn(const U16* __restrict__ qc, const U16* __restrict__ kvc,
                                                  const int* __restrict__ seg_ids, U16* __restrict__ oc) {
    const int tok = blockIdx.x;
    const int b = tok >> 11;
    const int w = threadIdx.x >> 6, lane = threadIdx.x & 63;
    const int h = blockIdx.y * 4 + w;
    const int seg = seg_ids[tok];
    const size_t qoff = (size_t)tok * 1024 + h * 64 + lane;
    float q = bf2f(qc[qoff]);
    float s[9];
#pragma unroll
    for (int jj = 0; jj < 9; jj++) {
        int j = seg - 8 + jj;
        float sc = -INFINITY;
        if (j >= 0) {
            float kv = bf2f(kvc[((size_t)(b * 512) + j) * 2048 + h * 64 + lane]);
            sc = q * kv;
            sc += __shfl_xor(sc, 1); sc += __shfl_xor(sc, 2); sc += __shfl_xor(sc, 4);
            sc += __shfl_xor(sc, 8); sc += __shfl_xor(sc, 16); sc += __shfl_xor(sc, 32);
            sc *= 0.125f;
        }
        s[jj] = sc;
    }
    float m = s[0];
#pragma unroll
    for (int jj = 1; jj < 9; jj++) m = fmaxf(m, s[jj]);
    float l = 0.f, o = 0.f;
#pragma unroll
    for (int jj = 0; jj < 9; jj++) {
        int j = seg - 8 + jj;
        if (j >= 0) {
            float p = __expf(s[jj] - m);
            l += p;
            o += p * bf2f(kvc[((size_t)(b * 512) + j) * 2048 + 1024 + h * 64 + lane]);
        }
    }
    oc[qoff] = f2bf(o / l);
}

extern "C" void kernel_launch(void* const* d_in, const int* in_sizes, int n_in,
                              void* d_out, int out_size, void* d_ws, size_t ws_size,
                              hipStream_t stream) {
    const float* x      = (const float*)d_in[0];
    const float* memory = (const float*)d_in[1];
    const int*   seg    = (const int*)d_in[2];
    const float* n1w    = (const float*)d_in[3];
    const float* W_dq   = (const float*)d_in[4];
    const float* W_uq   = (const float*)d_in[5];
    const float* W_dkv  = (const float*)d_in[6];
    const float* W_uk   = (const float*)d_in[7];
    const float* W_uv   = (const float*)d_in[8];
    const float* W_os   = (const float*)d_in[9];
    const float* n2w    = (const float*)d_in[10];
    const float* W_qc   = (const float*)d_in[11];
    const float* W_kc   = (const float*)d_in[12];
    const float* W_vc   = (const float*)d_in[13];
    const float* W_oc   = (const float*)d_in[14];
    const float* n3w    = (const float*)d_in[15];
    const float* W_gate = (const float*)d_in[16];
    const float* W_up   = (const float*)d_in[17];
    const float* W_down = (const float*)d_in[18];
    (void)in_sizes; (void)n_in; (void)out_size; (void)ws_size;

    char* ws = (char*)d_ws;
    size_t off = 0;
    auto alloc = [&](size_t bytes) -> void* {
        void* p = ws + off;
        off += (bytes + 255) & ~(size_t)255;
        return p;
    };
    const size_t MB = 1024 * 1024;
    U16* hbuf     = (U16*)alloc(8 * MB);
    float* x1     = (float*)alloc(16 * MB);
    float* x2     = (float*)alloc(16 * MB);
    float* cq32   = (float*)alloc(8 * MB);          // 4 split-K fp32 partials [4][4096*128]
    U16* Wt_dqkv  = (U16*)alloc(128 * 1024 * 2);
    U16* Wt_uqk   = (U16*)alloc(2048 * 128 * 2);
    U16* Wt_uv    = (U16*)alloc(1024 * 128 * 2);
    U16* Wt_os    = (U16*)alloc(1024 * 1024 * 2);
    U16* Wt_qc    = (U16*)alloc(1024 * 1024 * 2);
    U16* Wt_kvc   = (U16*)alloc((size_t)2048 * 1024 * 2);
    U16* Wt_oc    = (U16*)alloc(1024 * 1024 * 2);
    U16* Wt_gu    = (U16*)alloc((size_t)8192 * 1024 * 2);
    U16* Wt_down  = (U16*)alloc((size_t)1024 * 4096 * 2);
    U16* mem_bf   = (U16*)alloc(1024 * 1024 * 2);
    char* arena   = ws + off;
    // phase 1
    U16* cq  = (U16*)(arena);                  // [4096][128]
    U16* qkb = (U16*)(arena + 1 * MB);         // [4096][2048]
    U16* vt  = (U16*)(arena + 17 * MB);        // [1024][4096]
    U16* ob  = (U16*)(arena + 25 * MB);        // [4096][1024]
    // phase 2
    U16* qcb  = (U16*)(arena);                 // [4096][1024]
    U16* kvcb = (U16*)(arena + 8 * MB);        // [1024][2048]
    U16* ocb  = (U16*)(arena + 12 * MB);       // [4096][1024]
    // phase 3
    U16* gact = (U16*)(arena);                 // [4096][4096]

    // ---- merged weight prep
    WTable T;
    int i = 0;
    auto ent = [&](const float* s, U16* d, int K, int N, int Kpad, int Npad, int koff, int noff) {
        T.e[i++] = WEnt{s, d, K, N, Kpad, Npad, koff, noff, (Kpad >> 5) * (Npad >> 5)};
    };
    ent(W_dq,   Wt_dqkv, 1024, 32,   1024, 32,   0,  0);
    ent(W_dkv,  Wt_dqkv, 1024, 64,   1024, 96,   0,  32);
    ent(W_uq,   Wt_uqk,  32,   1024, 128,  1024, 0,  0);
    ent(W_uk,   Wt_uqk,  64,   1024, 128,  1024, 32, 1024);
    ent(W_uv,   Wt_uv,   64,   1024, 128,  1024, 32, 0);
    ent(W_os,   Wt_os,   1024, 1024, 1024, 1024, 0,  0);
    ent(W_qc,   Wt_qc,   1024, 1024, 1024, 1024, 0,  0);
    ent(W_kc,   Wt_kvc,  1024, 1024, 1024, 1024, 0,  0);
    ent(W_vc,   Wt_kvc,  1024, 1024, 1024, 1024, 0,  1024);
    ent(W_oc,   Wt_oc,   1024, 1024, 1024, 1024, 0,  0);
    ent(W_gate, Wt_gu,   1024, 4096, 1024, 4096, 0,  0);
    ent(W_up,   Wt_gu,   1024, 4096, 1024, 4096, 0,  4096);
    ent(W_down, Wt_down, 4096, 1024, 4096, 1024, 0,  0);
    int total_tiles = 0;
    for (int j = 0; j < 13; j++) total_tiles += T.e[j].tiles;
    wtrans_all<<<total_tiles, 256, 0, stream>>>(T);
    f2bf_k<<<1024, 256, 0, stream>>>(memory, mem_bf, 1024 * 1024);

    // ---- phase 1: self-attention block
    rmsnorm_k<<<4096, 256, 0, stream>>>(x, n1w, hbuf);
    gemm_m64<5><<<dim3(1, 64, 4), 256, 0, stream>>>(hbuf, Wt_dqkv, cq32, nullptr, 4096, 128, 256, 1024, 1024, 128);
    cq_reduce<<<512, 256, 0, stream>>>(cq32, cq);
    qkuv_gemm<<<dim3(24, 32), 256, 0, stream>>>(cq, Wt_uqk, Wt_uv, qkb, vt);
    flash_self4<<<512, 256, 0, stream>>>(qkb, vt, ob);
    gemm_m64<1><<<dim3(8, 64), 256, 0, stream>>>(ob, Wt_os, x1, x, 4096, 1024, 1024, 1024, 1024, 1024);

    // ---- phase 2: cross attention block
    rmsnorm_k<<<4096, 256, 0, stream>>>(x1, n2w, hbuf);
    qckv_gemm<<<768, 256, 0, stream>>>(hbuf, Wt_qc, mem_bf, Wt_kvc, qcb, kvcb);
    cross_attn<<<dim3(4096, 4), 256, 0, stream>>>(qcb, kvcb, seg, ocb);
    gemm_m64<1><<<dim3(8, 64), 256, 0, stream>>>(ocb, Wt_oc, x2, x1, 4096, 1024, 1024, 1024, 1024, 1024);

    // ---- phase 3: FFN (fused gate+up+silu 256x256 pipelined, then down)
    rmsnorm_k<<<4096, 256, 0, stream>>>(x2, n3w, hbuf);
    ffn1_8ph<<<dim3(32, 16), 512, 0, stream>>>(hbuf, Wt_gu, gact);
    gemm_m64<1><<<dim3(8, 64), 256, 0, stream>>>(gact, Wt_down, (float*)d_out, x2, 4096, 1024, 4096, 4096, 4096, 1024);
}

// Round 7
// 489.132 us; speedup vs baseline: 1.0354x; 1.0214x over previous
//
#include <hip/hip_runtime.h>
#include <stdint.h>

typedef unsigned short U16;
typedef __bf16 bf16x8 __attribute__((ext_vector_type(8)));
typedef unsigned short us8 __attribute__((ext_vector_type(8)));
typedef float f32x4 __attribute__((ext_vector_type(4)));

__device__ __forceinline__ U16 f2bf(float f) {
    unsigned u = __builtin_bit_cast(unsigned, f);
    unsigned r = (u + 0x7fff + ((u >> 16) & 1)) >> 16;
    return (U16)r;
}
__device__ __forceinline__ U16 f2bf_fast(float f) {   // round-half-up, for positive non-NaN
    return (U16)((__builtin_bit_cast(unsigned, f) + 0x8000u) >> 16);
}
__device__ __forceinline__ float bf2f(U16 v) {
    return __builtin_bit_cast(float, (unsigned)v << 16);
}
__device__ __forceinline__ bf16x8 ld8(const U16* p) { return __builtin_bit_cast(bf16x8, *(const us8*)p); }

// async global->LDS, 16B per lane; lds base wave-uniform, HW scatters lane i at base+i*16
__device__ __forceinline__ void async16(const U16* g, U16* l) {
    auto* gp = (const __attribute__((address_space(1))) U16*)g;
    auto* lp = (__attribute__((address_space(3))) U16*)(uintptr_t)(uint32_t)(uintptr_t)l;
    __builtin_amdgcn_global_load_lds(gp, lp, 16, 0, 0);
}

// ---------------- merged weight transpose: dst[noff+n][kk] = bf16(src[kk-koff][n]), zero-padded
struct WEnt { const float* src; U16* dst; int K, N, Kpad, Npad, koff, noff, tiles; };
struct WTable { WEnt e[13]; };

__global__ __launch_bounds__(256) void wtrans_all(WTable t) {
    int bx = blockIdx.x, ei = 0;
    while (bx >= t.e[ei].tiles) { bx -= t.e[ei].tiles; ei++; }
    const WEnt E = t.e[ei];
    const int ntn = E.Npad >> 5;
    const int n0 = (bx % ntn) * 32, k0 = (bx / ntn) * 32;
    __shared__ float tile[32][33];
    const int tx = threadIdx.x & 31, ty = threadIdx.x >> 5;
#pragma unroll
    for (int i = 0; i < 4; i++) {
        int kk = k0 + ty + i * 8, n = n0 + tx;
        int k = kk - E.koff;
        float v = (k >= 0 && k < E.K && n < E.N) ? E.src[(size_t)k * E.N + n] : 0.f;
        tile[ty + i * 8][tx] = v;
    }
    __syncthreads();
#pragma unroll
    for (int i = 0; i < 4; i++) {
        int n = n0 + ty + i * 8, kk = k0 + tx;
        E.dst[(size_t)(E.noff + n) * E.Kpad + kk] = f2bf(tile[tx][ty + i * 8]);
    }
}

// ---------------- fp32 -> bf16 convert
__global__ __launch_bounds__(256) void f2bf_k(const float* __restrict__ in, U16* __restrict__ out, int n) {
    int i = (blockIdx.x * 256 + threadIdx.x) * 4;
    if (i < n) {
        float4 v = *(const float4*)(in + i);
        out[i + 0] = f2bf(v.x); out[i + 1] = f2bf(v.y);
        out[i + 2] = f2bf(v.z); out[i + 3] = f2bf(v.w);
    }
}

// ---------------- reduce 4 fp32 partials [4][4096*128] -> bf16
__global__ __launch_bounds__(256) void cq_reduce(const float* __restrict__ p, U16* __restrict__ out) {
    int i = (blockIdx.x * 256 + threadIdx.x) * 4;
    const float4 a = *(const float4*)(p + i);
    const float4 b = *(const float4*)(p + 524288 + i);
    const float4 c = *(const float4*)(p + 2 * 524288 + i);
    const float4 d = *(const float4*)(p + 3 * 524288 + i);
    out[i + 0] = f2bf(a.x + b.x + c.x + d.x);
    out[i + 1] = f2bf(a.y + b.y + c.y + d.y);
    out[i + 2] = f2bf(a.z + b.z + c.z + d.z);
    out[i + 3] = f2bf(a.w + b.w + c.w + d.w);
}

// ---------------- RMSNorm: fp32 row (1024) -> bf16
__global__ __launch_bounds__(256) void rmsnorm_k(const float* __restrict__ x, const float* __restrict__ w,
                                                 U16* __restrict__ h) {
    const int row = blockIdx.x, tid = threadIdx.x;
    const float4 v = *(const float4*)(x + (size_t)row * 1024 + tid * 4);
    float ss = v.x * v.x + v.y * v.y + v.z * v.z + v.w * v.w;
#pragma unroll
    for (int o = 32; o > 0; o >>= 1) ss += __shfl_xor(ss, o);
    __shared__ float red[4];
    if ((tid & 63) == 0) red[tid >> 6] = ss;
    __syncthreads();
    float tot = red[0] + red[1] + red[2] + red[3];
    float sc = rsqrtf(tot * (1.0f / 1024.0f) + 1e-6f);
    const float4 wv = *(const float4*)(w + tid * 4);
    U16* hp = h + (size_t)row * 1024 + tid * 4;
    hp[0] = f2bf(v.x * sc * wv.x); hp[1] = f2bf(v.y * sc * wv.y);
    hp[2] = f2bf(v.z * sc * wv.z); hp[3] = f2bf(v.w * sc * wv.w);
}

// ---------------- merged uq/uk + uv GEMM from cq [4096][128], K=128
// grid (24, 32): x<16 -> qkb bf16 [4096][2048]; x>=16 -> vt transposed bf16 [1024][4096]
__global__ __launch_bounds__(256) void qkuv_gemm(const U16* __restrict__ A, const U16* __restrict__ Wuqk,
                                                 const U16* __restrict__ Wuv,
                                                 U16* __restrict__ qkb, U16* __restrict__ vt) {
    __shared__ __align__(16) U16 As[2][128 * 32];
    __shared__ __align__(16) U16 Bs[2][128 * 32];
    __shared__ __align__(16) U16 Ts[4][64 * 80];
    const int tid = threadIdx.x;
    const bool isuv = blockIdx.x >= 16;
    const U16* Bt = isuv ? Wuv : Wuqk;
    const int n0 = (isuv ? blockIdx.x - 16 : blockIdx.x) * 128;
    const int m0 = blockIdx.y * 128;
    const int wave = tid >> 6, lane = tid & 63, l16 = lane & 15, quad = lane >> 4;
    const int wm = (wave >> 1) * 64, wn = (wave & 1) * 64;
    const int sr = lane >> 2, sc = (lane & 3) * 8;
    const U16* gA = A + (size_t)(m0 + wave * 32 + sr) * 128 + sc;
    const U16* gB = Bt + (size_t)(n0 + wave * 32 + sr) * 128 + sc;
    f32x4 acc[4][4] = {};
    for (int kt = 0; kt < 128; kt += 64) {
        __syncthreads();
#pragma unroll
        for (int p = 0; p < 2; p++) {
            const int o = kt + p * 32;
            async16(gA + o, &As[p][(wave * 32) * 32]);
            async16(gA + 16 * 128 + o, &As[p][(wave * 32 + 16) * 32]);
            async16(gB + o, &Bs[p][(wave * 32) * 32]);
            async16(gB + 16 * 128 + o, &Bs[p][(wave * 32 + 16) * 32]);
        }
        __syncthreads();
#pragma unroll
        for (int p = 0; p < 2; p++) {
            bf16x8 af[4], bfr[4];
#pragma unroll
            for (int i = 0; i < 4; i++) {
                af[i]  = ld8(&As[p][(wm + i * 16 + l16) * 32 + quad * 8]);
                bfr[i] = ld8(&Bs[p][(wn + i * 16 + l16) * 32 + quad * 8]);
            }
#pragma unroll
            for (int mi = 0; mi < 4; mi++)
#pragma unroll
                for (int ni = 0; ni < 4; ni++)
                    acc[mi][ni] = __builtin_amdgcn_mfma_f32_16x16x32_bf16(af[mi], bfr[ni], acc[mi][ni], 0, 0, 0);
        }
    }
    if (isuv) {
        // per-wave LDS transpose -> coalesced 16B stores along m into vt [1024][4096]
        U16* T = Ts[wave];
#pragma unroll
        for (int mi = 0; mi < 4; mi++)
#pragma unroll
            for (int ni = 0; ni < 4; ni++)
#pragma unroll
                for (int r = 0; r < 4; r++)
                    T[(ni * 16 + l16) * 80 + mi * 16 + quad * 4 + r] = f2bf(acc[mi][ni][r]);
#pragma unroll
        for (int c = 0; c < 8; c++) {
            int nloc = (lane >> 3) + 8 * c, mloc = (lane & 7) * 8;
            us8 v = *(const us8*)&T[nloc * 80 + mloc];
            *(us8*)&vt[(size_t)(n0 + wn + nloc) * 4096 + (m0 + wm + mloc)] = v;
        }
    } else {
#pragma unroll
        for (int mi = 0; mi < 4; mi++)
#pragma unroll
            for (int r = 0; r < 4; r++) {
                int m = m0 + wm + mi * 16 + quad * 4 + r;
#pragma unroll
                for (int ni = 0; ni < 4; ni++)
                    qkb[(size_t)m * 2048 + n0 + wn + ni * 16 + l16] = f2bf(acc[mi][ni][r]);
            }
    }
}

// ---------------- 128x128 GEMM, 4 waves, per-wave 64x64, BK=64 dbuf, XOR-swizzled LDS, counted vmcnt
// EPI 0: bf16. EPI 1: fp32 = resid + acc. EPI 5: fp32 partial at Cout + z*524288 (no resid).
template <int EPI>
__global__ __launch_bounds__(256) void gemm_m128(const U16* __restrict__ A, const U16* __restrict__ Bt,
                                                 void* __restrict__ Cout, const float* __restrict__ resid,
                                                 int M, int N, int K, int lda, int ldb, int ldc) {
    __shared__ __align__(16) U16 As[2][128 * 64];
    __shared__ __align__(16) U16 Bs[2][128 * 64];
    const int tid = threadIdx.x;
    const int m0 = blockIdx.y * 128, n0 = blockIdx.x * 128;
    const int k0 = blockIdx.z * K;
    const int wave = tid >> 6, lane = tid & 63, l16 = lane & 15, quad = lane >> 4;
    const int wm = (wave >> 1) * 64, wn = (wave & 1) * 64;
    const int srow = lane >> 3;               // 0..7
    const int schunk = (lane & 7) ^ srow;     // inverse-swizzled source 16B-chunk (ffn1-verified)
    const U16* gA = A + (size_t)(m0 + wave * 32 + srow) * lda + schunk * 8 + k0;
    const U16* gB = Bt + (size_t)(n0 + wave * 32 + srow) * ldb + schunk * 8 + k0;

    auto STAGE = [&](int buf, int kt) {       // 8 global_load_lds per wave
        U16* la = &As[buf][(wave * 32) * 64];
        U16* lb = &Bs[buf][(wave * 32) * 64];
#pragma unroll
        for (int j = 0; j < 4; ++j) {
            async16(gA + kt + (size_t)j * 8 * lda, la + j * 8 * 64);
            async16(gB + kt + (size_t)j * 8 * ldb, lb + j * 8 * 64);
        }
    };

    f32x4 acc[4][4] = {};
    const int NTK = K >> 6;                   // >= 2 for all call sites
    STAGE(0, 0);
    STAGE(1, 64);
#pragma unroll 1
    for (int t = 0; t < NTK; ++t) {
        if (t == NTK - 1) asm volatile("s_waitcnt vmcnt(0)" ::: "memory");
        else              asm volatile("s_waitcnt vmcnt(8)" ::: "memory");
        __builtin_amdgcn_s_barrier();
        __builtin_amdgcn_sched_barrier(0);
        const int buf = t & 1;
        const int cx = l16 & 7;
        bf16x8 af[4][2], bfr[4][2];
#pragma unroll
        for (int i = 0; i < 4; ++i)
#pragma unroll
            for (int kh = 0; kh < 2; ++kh) {
                af[i][kh]  = ld8(&As[buf][(wm + i * 16 + l16) * 64 + (((kh * 4 + quad) ^ cx) << 3)]);
                bfr[i][kh] = ld8(&Bs[buf][(wn + i * 16 + l16) * 64 + (((kh * 4 + quad) ^ cx) << 3)]);
            }
        __builtin_amdgcn_s_setprio(1);
#pragma unroll
        for (int mi = 0; mi < 4; ++mi)
#pragma unroll
            for (int ni = 0; ni < 4; ++ni)
#pragma unroll
                for (int kh = 0; kh < 2; ++kh)
                    acc[mi][ni] = __builtin_amdgcn_mfma_f32_16x16x32_bf16(af[mi][kh], bfr[ni][kh], acc[mi][ni], 0, 0, 0);
        __builtin_amdgcn_s_setprio(0);
        __builtin_amdgcn_s_barrier();         // all waves done reading buf
        if (t + 2 < NTK) STAGE(buf, (t + 2) * 64);
    }
#pragma unroll
    for (int mi = 0; mi < 4; ++mi) {
#pragma unroll
        for (int r = 0; r < 4; ++r) {
            int m = m0 + wm + mi * 16 + quad * 4 + r;
#pragma unroll
            for (int ni = 0; ni < 4; ++ni) {
                int n = n0 + wn + ni * 16 + l16;
                float val = acc[mi][ni][r];
                if (EPI == 0) ((U16*)Cout)[(size_t)m * ldc + n] = f2bf(val);
                else if (EPI == 1) ((float*)Cout)[(size_t)m * ldc + n] = resid[(size_t)m * ldc + n] + val;
                else if (EPI == 5) ((float*)Cout)[(size_t)blockIdx.z * 524288 + (size_t)m * ldc + n] = val;
            }
        }
    }
}

// ---------------- merged qc + kvc GEMM, 128x128 structure (K=1024, lda=ldb=1024)
// 384 blocks: [0,256) -> qcb [4096][1024]; [256,384) -> kvcb [1024][2048]
__global__ __launch_bounds__(256) void qckv_gemm(const U16* __restrict__ hbuf, const U16* __restrict__ Wqc,
                                                 const U16* __restrict__ memb, const U16* __restrict__ Wkvc,
                                                 U16* __restrict__ qcb, U16* __restrict__ kvcb) {
    __shared__ __align__(16) U16 As[2][128 * 64];
    __shared__ __align__(16) U16 Bs[2][128 * 64];
    const int tid = threadIdx.x, bid = blockIdx.x;
    const U16 *A, *Bt; U16* C; int m0, n0, ldc;
    if (bid < 256) { A = hbuf; Bt = Wqc;  C = qcb;  m0 = (bid >> 3) * 128; n0 = (bid & 7) * 128;  ldc = 1024; }
    else { int b2 = bid - 256; A = memb; Bt = Wkvc; C = kvcb; m0 = (b2 >> 4) * 128; n0 = (b2 & 15) * 128; ldc = 2048; }
    const int wave = tid >> 6, lane = tid & 63, l16 = lane & 15, quad = lane >> 4;
    const int wm = (wave >> 1) * 64, wn = (wave & 1) * 64;
    const int srow = lane >> 3;
    const int schunk = (lane & 7) ^ srow;
    const U16* gA = A + (size_t)(m0 + wave * 32 + srow) * 1024 + schunk * 8;
    const U16* gB = Bt + (size_t)(n0 + wave * 32 + srow) * 1024 + schunk * 8;

    auto STAGE = [&](int buf, int kt) {
        U16* la = &As[buf][(wave * 32) * 64];
        U16* lb = &Bs[buf][(wave * 32) * 64];
#pragma unroll
        for (int j = 0; j < 4; ++j) {
            async16(gA + kt + (size_t)j * 8 * 1024, la + j * 8 * 64);
            async16(gB + kt + (size_t)j * 8 * 1024, lb + j * 8 * 64);
        }
    };

    f32x4 acc[4][4] = {};
    STAGE(0, 0);
    STAGE(1, 64);
#pragma unroll 1
    for (int t = 0; t < 16; ++t) {
        if (t == 15) asm volatile("s_waitcnt vmcnt(0)" ::: "memory");
        else         asm volatile("s_waitcnt vmcnt(8)" ::: "memory");
        __builtin_amdgcn_s_barrier();
        __builtin_amdgcn_sched_barrier(0);
        const int buf = t & 1;
        const int cx = l16 & 7;
        bf16x8 af[4][2], bfr[4][2];
#pragma unroll
        for (int i = 0; i < 4; ++i)
#pragma unroll
            for (int kh = 0; kh < 2; ++kh) {
                af[i][kh]  = ld8(&As[buf][(wm + i * 16 + l16) * 64 + (((kh * 4 + quad) ^ cx) << 3)]);
                bfr[i][kh] = ld8(&Bs[buf][(wn + i * 16 + l16) * 64 + (((kh * 4 + quad) ^ cx) << 3)]);
            }
        __builtin_amdgcn_s_setprio(1);
#pragma unroll
        for (int mi = 0; mi < 4; ++mi)
#pragma unroll
            for (int ni = 0; ni < 4; ++ni)
#pragma unroll
                for (int kh = 0; kh < 2; ++kh)
                    acc[mi][ni] = __builtin_amdgcn_mfma_f32_16x16x32_bf16(af[mi][kh], bfr[ni][kh], acc[mi][ni], 0, 0, 0);
        __builtin_amdgcn_s_setprio(0);
        __builtin_amdgcn_s_barrier();
        if (t + 2 < 16) STAGE(buf, (t + 2) * 64);
    }
#pragma unroll
    for (int mi = 0; mi < 4; ++mi)
#pragma unroll
        for (int r = 0; r < 4; ++r) {
            int m = m0 + wm + mi * 16 + quad * 4 + r;
#pragma unroll
            for (int ni = 0; ni < 4; ++ni)
                C[(size_t)m * ldc + n0 + wn + ni * 16 + l16] = f2bf(acc[mi][ni][r]);
        }
}

// ---------------- fused FFN1, 256x256 deep-pipelined (T2 swizzle + T3/T4 counted vmcnt + T5 setprio)
// Round-4 coarse-TILE schedule — per-phase barriers regressed (R5), reverted.
__global__ __launch_bounds__(512, 2) void ffn1_8ph(const U16* __restrict__ A, const U16* __restrict__ Wgu,
                                                   U16* __restrict__ Cout) {
    __shared__ __align__(16) U16 As[2][256 * 64];
    __shared__ __align__(16) U16 Bs[2][256 * 64];
    const int tid = threadIdx.x;
    const int wid = tid >> 6, lane = tid & 63;
    const int l16 = lane & 15, quad = lane >> 4;
    const int n0 = blockIdx.x * 128;          // output col tile
    const int m0 = blockIdx.y * 256;          // row tile
    const int wr = wid >> 2, wc = wid & 3;
    const int wm = wr * 128;                  // wave m offset in tile
    const int wn = wc * 64;                   // wave B-row offset in tile
    const int srow = lane >> 3;               // 0..7
    const int schunk = (lane & 7) ^ srow;     // inverse-swizzled source chunk
    const U16* gA = A + (size_t)(m0 + wid * 32 + srow) * 1024 + schunk * 8;
    const U16* gB = Wgu + (size_t)((wid & 1) * 4096 + n0 + (wid >> 1) * 32 + srow) * 1024 + schunk * 8;

    auto STAGE = [&](int buf, int kt) {       // 8 global_load_lds per wave
        U16* la = &As[buf][(wid * 32) * 64];
        U16* lb = &Bs[buf][(wid * 32) * 64];
        const U16* pa = gA + kt;
        const U16* pb = gB + kt;
#pragma unroll
        for (int j = 0; j < 4; ++j) {
            async16(pa + j * 8 * 1024, la + j * 8 * 64);
            async16(pb + j * 8 * 1024, lb + j * 8 * 64);
        }
    };

    f32x4 acc[8][4] = {};                     // [mi][ni]; ni 0,1 = gate frags, 2,3 = up frags

    auto TILE = [&](int buf) {
        const U16* Ab = &As[buf][0];
        const U16* Bb = &Bs[buf][0];
        const int cx = l16 & 7;               // read-side swizzle XOR
        bf16x8 a0[4][2], a1[4][2], b0[2][2], b1[2][2];
#pragma unroll
        for (int mi = 0; mi < 4; ++mi)
#pragma unroll
            for (int kh = 0; kh < 2; ++kh)
                a0[mi][kh] = ld8(&Ab[(wm + mi * 16 + l16) * 64 + (((kh * 4 + quad) ^ cx) << 3)]);
#pragma unroll
        for (int ni = 0; ni < 2; ++ni)
#pragma unroll
            for (int kh = 0; kh < 2; ++kh)
                b0[ni][kh] = ld8(&Bb[(wn + ni * 16 + l16) * 64 + (((kh * 4 + quad) ^ cx) << 3)]);
#pragma unroll
        for (int ni = 0; ni < 2; ++ni)
#pragma unroll
            for (int kh = 0; kh < 2; ++kh)
                b1[ni][kh] = ld8(&Bb[(wn + 32 + ni * 16 + l16) * 64 + (((kh * 4 + quad) ^ cx) << 3)]);
        __builtin_amdgcn_s_setprio(1);
#pragma unroll
        for (int mi = 0; mi < 4; ++mi)
#pragma unroll
            for (int ni = 0; ni < 2; ++ni)
#pragma unroll
                for (int kh = 0; kh < 2; ++kh)
                    acc[mi][ni] = __builtin_amdgcn_mfma_f32_16x16x32_bf16(a0[mi][kh], b0[ni][kh], acc[mi][ni], 0, 0, 0);
        __builtin_amdgcn_s_setprio(0);
#pragma unroll
        for (int mi = 0; mi < 4; ++mi)
#pragma unroll
            for (int kh = 0; kh < 2; ++kh)
                a1[mi][kh] = ld8(&Ab[(wm + 64 + mi * 16 + l16) * 64 + (((kh * 4 + quad) ^ cx) << 3)]);
        __builtin_amdgcn_s_setprio(1);
#pragma unroll
        for (int mi = 0; mi < 4; ++mi)
#pragma unroll
            for (int ni = 0; ni < 2; ++ni)
#pragma unroll
                for (int kh = 0; kh < 2; ++kh)
                    acc[mi][2 + ni] = __builtin_amdgcn_mfma_f32_16x16x32_bf16(a0[mi][kh], b1[ni][kh], acc[mi][2 + ni], 0, 0, 0);
        __builtin_amdgcn_s_setprio(0);
        __builtin_amdgcn_s_setprio(1);
#pragma unroll
        for (int mi = 0; mi < 4; ++mi)
#pragma unroll
            for (int ni = 0; ni < 2; ++ni)
#pragma unroll
                for (int kh = 0; kh < 2; ++kh)
                    acc[4 + mi][2 + ni] = __builtin_amdgcn_mfma_f32_16x16x32_bf16(a1[mi][kh], b1[ni][kh], acc[4 + mi][2 + ni], 0, 0, 0);
        __builtin_amdgcn_s_setprio(0);
        __builtin_amdgcn_s_setprio(1);
#pragma unroll
        for (int mi = 0; mi < 4; ++mi)
#pragma unroll
            for (int ni = 0; ni < 2; ++ni)
#pragma unroll
                for (int kh = 0; kh < 2; ++kh)
                    acc[4 + mi][ni] = __builtin_amdgcn_mfma_f32_16x16x32_bf16(a1[mi][kh], b0[ni][kh], acc[4 + mi][ni], 0, 0, 0);
        __builtin_amdgcn_s_setprio(0);
    };

    STAGE(0, 0);
    STAGE(1, 64);
#pragma unroll 1
    for (int t2 = 0; t2 < 7; ++t2) {
        asm volatile("s_waitcnt vmcnt(8)" ::: "memory");
        __builtin_amdgcn_s_barrier();
        __builtin_amdgcn_sched_barrier(0);
        TILE(0);
        __builtin_amdgcn_s_barrier();
        STAGE(0, (2 * t2 + 2) * 64);
        asm volatile("s_waitcnt vmcnt(8)" ::: "memory");
        __builtin_amdgcn_s_barrier();
        __builtin_amdgcn_sched_barrier(0);
        TILE(1);
        __builtin_amdgcn_s_barrier();
        STAGE(1, (2 * t2 + 3) * 64);
    }
    asm volatile("s_waitcnt vmcnt(8)" ::: "memory");
    __builtin_amdgcn_s_barrier();
    __builtin_amdgcn_sched_barrier(0);
    TILE(0);
    asm volatile("s_waitcnt vmcnt(0)" ::: "memory");
    __builtin_amdgcn_s_barrier();
    __builtin_amdgcn_sched_barrier(0);
    TILE(1);

#pragma unroll
    for (int mi = 0; mi < 8; ++mi)
#pragma unroll
        for (int r = 0; r < 4; ++r) {
            int m = m0 + wm + mi * 16 + quad * 4 + r;
#pragma unroll
            for (int ni = 0; ni < 2; ++ni) {
                int col = n0 + wc * 32 + ni * 16 + l16;
                float g = acc[mi][ni][r], u = acc[mi][ni + 2][r];
                float act = g / (1.f + __expf(-g)) * u;
                Cout[(size_t)m * 4096 + col] = f2bf(act);
            }
        }
}

// ---------------- flash self-attention v4: LDS-staged K/V, double-buffered, counted vmcnt
__global__ __launch_bounds__(256, 3) void flash_self4(const U16* __restrict__ QK, const U16* __restrict__ Vt,
                                                      U16* __restrict__ Og) {
    __shared__ __align__(16) U16 Ks[2][32 * 64];
    __shared__ __align__(16) U16 Vs[2][64 * 32];
    __shared__ __align__(16) U16 Ps[4][1280];
    const int wave = threadIdx.x >> 6, lane = threadIdx.x & 63;
    const int l16 = lane & 15, quad = lane >> 4;
    const int bx = blockIdx.x;
    const int T = 15 - (bx >> 5);             // heavy tiles first
    const int bh = bx & 31, b = bh >> 4, h = bh & 15;
    const int q0 = T * 128;
    const int NT = 4 * T + 4;                 // number of 32-wide j-tiles
    const int G0 = q0 + wave * 16, G1 = q0 + 64 + wave * 16;
    bf16x8 aq[2][2];
    {
        const size_t r0 = (size_t)(b * 2048 + G0 + l16) * 2048 + h * 64;
        const size_t r1 = (size_t)(b * 2048 + G1 + l16) * 2048 + h * 64;
        aq[0][0] = ld8(QK + r0 + quad * 8); aq[0][1] = ld8(QK + r0 + 32 + quad * 8);
        aq[1][0] = ld8(QK + r1 + quad * 8); aq[1][1] = ld8(QK + r1 + 32 + quad * 8);
    }
    const int krow = wave * 8 + (lane >> 3);                               // K tile row
    const int kchunk = (lane & 7) ^ (lane >> 3);                           // ^ (krow&7)
    const U16* gK = QK + (size_t)(b * 2048 + krow) * 2048 + 1024 + h * 64 + kchunk * 8;
    const int vrow = wave * 16 + (lane >> 2);                              // V tile row (d)
    const int vchunk = (lane & 3) ^ ((lane >> 2) & 3) ^ ((lane >> 4) & 3); // ^ (vr&3)^((vr>>2)&3)
    const U16* gV = Vt + (size_t)(h * 64 + vrow) * 4096 + b * 2048 + vchunk * 8;

    auto STAGE = [&](int buf, int j0) {       // 2 global_load_lds per wave
        async16(gK + (size_t)j0 * 2048, &Ks[buf][(wave * 8) * 64]);
        async16(gV + j0, &Vs[buf][(wave * 16) * 32]);
    };

    f32x4 o[2][4] = {};
    float ls[2][4] = {};
    U16* Pw = Ps[wave];
    const int prd = l16 * 40 + ((quad ^ (l16 >> 2)) << 3);

    auto TILE = [&](int buf, int j0) {
        bf16x8 kf[2][2];
#pragma unroll
        for (int jh = 0; jh < 2; ++jh)
#pragma unroll
            for (int kh = 0; kh < 2; ++kh)
                kf[jh][kh] = ld8(&Ks[buf][(jh * 16 + l16) * 64 + (((kh * 4 + quad) ^ (l16 & 7)) << 3)]);
        bf16x8 vf[4];
#pragma unroll
        for (int dg = 0; dg < 4; ++dg)
            vf[dg] = ld8(&Vs[buf][(dg * 16 + l16) * 32 + ((quad ^ (l16 & 3) ^ ((l16 >> 2) & 3)) << 3)]);
#pragma unroll
        for (int g = 0; g < 2; ++g) {
            const int G = g ? G1 : G0;
            if (j0 < G + 16) {                // group has unmasked rows in this tile
                f32x4 s0 = {}, s1 = {};
                __builtin_amdgcn_s_setprio(1);
                s0 = __builtin_amdgcn_mfma_f32_16x16x32_bf16(aq[g][0], kf[0][0], s0, 0, 0, 0);
                s0 = __builtin_amdgcn_mfma_f32_16x16x32_bf16(aq[g][1], kf[0][1], s0, 0, 0, 0);
                s1 = __builtin_amdgcn_mfma_f32_16x16x32_bf16(aq[g][0], kf[1][0], s1, 0, 0, 0);
                s1 = __builtin_amdgcn_mfma_f32_16x16x32_bf16(aq[g][1], kf[1][1], s1, 0, 0, 0);
                __builtin_amdgcn_s_setprio(0);
                float p0[4], p1[4];
                if (j0 + 32 > G) {            // diagonal tile: apply causal mask
#pragma unroll
                    for (int r = 0; r < 4; ++r) {
                        int qg = G + quad * 4 + r;
                        p0[r] = (j0 + l16 <= qg) ? __expf(fminf(s0[r] * 0.125f, 30.f)) : 0.f;
                        p1[r] = (j0 + 16 + l16 <= qg) ? __expf(fminf(s1[r] * 0.125f, 30.f)) : 0.f;
                    }
                } else {
#pragma unroll
                    for (int r = 0; r < 4; ++r) {
                        p0[r] = __expf(fminf(s0[r] * 0.125f, 30.f));
                        p1[r] = __expf(fminf(s1[r] * 0.125f, 30.f));
                    }
                }
#pragma unroll
                for (int r = 0; r < 4; ++r) {
                    ls[g][r] += p0[r] + p1[r];
                    int row = quad * 4 + r;
                    Pw[g * 640 + row * 40 + ((((l16 >> 3) + 0) ^ quad) << 3) + (l16 & 7)] = f2bf_fast(p0[r]);
                    Pw[g * 640 + row * 40 + ((((l16 >> 3) + 2) ^ quad) << 3) + (l16 & 7)] = f2bf_fast(p1[r]);
                }
                bf16x8 ap = ld8(&Pw[g * 640 + prd]);
                __builtin_amdgcn_s_setprio(1);
                o[g][0] = __builtin_amdgcn_mfma_f32_16x16x32_bf16(ap, vf[0], o[g][0], 0, 0, 0);
                o[g][1] = __builtin_amdgcn_mfma_f32_16x16x32_bf16(ap, vf[1], o[g][1], 0, 0, 0);
                o[g][2] = __builtin_amdgcn_mfma_f32_16x16x32_bf16(ap, vf[2], o[g][2], 0, 0, 0);
                o[g][3] = __builtin_amdgcn_mfma_f32_16x16x32_bf16(ap, vf[3], o[g][3], 0, 0, 0);
                __builtin_amdgcn_s_setprio(0);
            }
        }
    };

    STAGE(0, 0);
    STAGE(1, 32);
#pragma unroll 1
    for (int it = 0; it < NT - 2; ++it) {
        asm volatile("s_waitcnt vmcnt(2)" ::: "memory");
        __builtin_amdgcn_s_barrier();
        __builtin_amdgcn_sched_barrier(0);
        TILE(it & 1, it * 32);
        __builtin_amdgcn_s_barrier();
        STAGE(it & 1, (it + 2) * 32);
    }
    asm volatile("s_waitcnt vmcnt(2)" ::: "memory");
    __builtin_amdgcn_s_barrier();
    __builtin_amdgcn_sched_barrier(0);
    TILE(NT & 1, (NT - 2) * 32);
    asm volatile("s_waitcnt vmcnt(0)" ::: "memory");
    __builtin_amdgcn_s_barrier();
    __builtin_amdgcn_sched_barrier(0);
    TILE((NT - 1) & 1, (NT - 1) * 32);

#pragma unroll
    for (int g = 0; g < 2; ++g) {
        const int G = g ? G1 : G0;
#pragma unroll
        for (int r = 0; r < 4; ++r) {
            float v = ls[g][r];
            v += __shfl_xor(v, 1); v += __shfl_xor(v, 2);
            v += __shfl_xor(v, 4); v += __shfl_xor(v, 8);
            float inv = 1.0f / v;
            int qrow = G + quad * 4 + r;
            U16* op = Og + (size_t)(b * 2048 + qrow) * 1024 + h * 64 + l16;
#pragma unroll
            for (int dg = 0; dg < 4; ++dg)
                op[dg * 16] = f2bf(o[g][dg][r] * inv);
        }
    }
}

// ---------------- sliding-window cross attention (9 kv per query)
__global__ __launch_bounds__(256) void cross_attn(const U16* __restrict__ qc, const U16* __restrict__ kvc,
                                                  const int* __restrict__ seg_ids, U16* __restrict__ oc) {
    const int tok = blockIdx.x;
    const int b = tok >> 11;
    const int w = threadIdx.x >> 6, lane = threadIdx.x & 63;
    const int h = blockIdx.y * 4 + w;
    const int seg = seg_ids[tok];
    const size_t qoff = (size_t)tok * 1024 + h * 64 + lane;
    float q = bf2f(qc[qoff]);
    float s[9];
#pragma unroll
    for (int jj = 0; jj < 9; jj++) {
        int j = seg - 8 + jj;
        float sc = -INFINITY;
        if (j >= 0) {
            float kv = bf2f(kvc[((size_t)(b * 512) + j) * 2048 + h * 64 + lane]);
            sc = q * kv;
            sc += __shfl_xor(sc, 1); sc += __shfl_xor(sc, 2); sc += __shfl_xor(sc, 4);
            sc += __shfl_xor(sc, 8); sc += __shfl_xor(sc, 16); sc += __shfl_xor(sc, 32);
            sc *= 0.125f;
        }
        s[jj] = sc;
    }
    float m = s[0];
#pragma unroll
    for (int jj = 1; jj < 9; jj++) m = fmaxf(m, s[jj]);
    float l = 0.f, o = 0.f;
#pragma unroll
    for (int jj = 0; jj < 9; jj++) {
        int j = seg - 8 + jj;
        if (j >= 0) {
            float p = __expf(s[jj] - m);
            l += p;
            o += p * bf2f(kvc[((size_t)(b * 512) + j) * 2048 + 1024 + h * 64 + lane]);
        }
    }
    oc[qoff] = f2bf(o / l);
}

extern "C" void kernel_launch(void* const* d_in, const int* in_sizes, int n_in,
                              void* d_out, int out_size, void* d_ws, size_t ws_size,
                              hipStream_t stream) {
    const float* x      = (const float*)d_in[0];
    const float* memory = (const float*)d_in[1];
    const int*   seg    = (const int*)d_in[2];
    const float* n1w    = (const float*)d_in[3];
    const float* W_dq   = (const float*)d_in[4];
    const float* W_uq   = (const float*)d_in[5];
    const float* W_dkv  = (const float*)d_in[6];
    const float* W_uk   = (const float*)d_in[7];
    const float* W_uv   = (const float*)d_in[8];
    const float* W_os   = (const float*)d_in[9];
    const float* n2w    = (const float*)d_in[10];
    const float* W_qc   = (const float*)d_in[11];
    const float* W_kc   = (const float*)d_in[12];
    const float* W_vc   = (const float*)d_in[13];
    const float* W_oc   = (const float*)d_in[14];
    const float* n3w    = (const float*)d_in[15];
    const float* W_gate = (const float*)d_in[16];
    const float* W_up   = (const float*)d_in[17];
    const float* W_down = (const float*)d_in[18];
    (void)in_sizes; (void)n_in; (void)out_size; (void)ws_size;

    char* ws = (char*)d_ws;
    size_t off = 0;
    auto alloc = [&](size_t bytes) -> void* {
        void* p = ws + off;
        off += (bytes + 255) & ~(size_t)255;
        return p;
    };
    const size_t MB = 1024 * 1024;
    U16* hbuf     = (U16*)alloc(8 * MB);
    float* x1     = (float*)alloc(16 * MB);
    float* x2     = (float*)alloc(16 * MB);
    float* cq32   = (float*)alloc(8 * MB);          // 4 split-K fp32 partials [4][4096*128]
    U16* Wt_dqkv  = (U16*)alloc(128 * 1024 * 2);
    U16* Wt_uqk   = (U16*)alloc(2048 * 128 * 2);
    U16* Wt_uv    = (U16*)alloc(1024 * 128 * 2);
    U16* Wt_os    = (U16*)alloc(1024 * 1024 * 2);
    U16* Wt_qc    = (U16*)alloc(1024 * 1024 * 2);
    U16* Wt_kvc   = (U16*)alloc((size_t)2048 * 1024 * 2);
    U16* Wt_oc    = (U16*)alloc(1024 * 1024 * 2);
    U16* Wt_gu    = (U16*)alloc((size_t)8192 * 1024 * 2);
    U16* Wt_down  = (U16*)alloc((size_t)1024 * 4096 * 2);
    U16* mem_bf   = (U16*)alloc(1024 * 1024 * 2);
    char* arena   = ws + off;
    // phase 1
    U16* cq  = (U16*)(arena);                  // [4096][128]
    U16* qkb = (U16*)(arena + 1 * MB);         // [4096][2048]
    U16* vt  = (U16*)(arena + 17 * MB);        // [1024][4096]
    U16* ob  = (U16*)(arena + 25 * MB);        // [4096][1024]
    // phase 2
    U16* qcb  = (U16*)(arena);                 // [4096][1024]
    U16* kvcb = (U16*)(arena + 8 * MB);        // [1024][2048]
    U16* ocb  = (U16*)(arena + 12 * MB);       // [4096][1024]
    // phase 3
    U16* gact = (U16*)(arena);                 // [4096][4096]

    // ---- merged weight prep
    WTable T;
    int i = 0;
    auto ent = [&](const float* s, U16* d, int K, int N, int Kpad, int Npad, int koff, int noff) {
        T.e[i++] = WEnt{s, d, K, N, Kpad, Npad, koff, noff, (Kpad >> 5) * (Npad >> 5)};
    };
    ent(W_dq,   Wt_dqkv, 1024, 32,   1024, 32,   0,  0);
    ent(W_dkv,  Wt_dqkv, 1024, 64,   1024, 96,   0,  32);
    ent(W_uq,   Wt_uqk,  32,   1024, 128,  1024, 0,  0);
    ent(W_uk,   Wt_uqk,  64,   1024, 128,  1024, 32, 1024);
    ent(W_uv,   Wt_uv,   64,   1024, 128,  1024, 32, 0);
    ent(W_os,   Wt_os,   1024, 1024, 1024, 1024, 0,  0);
    ent(W_qc,   Wt_qc,   1024, 1024, 1024, 1024, 0,  0);
    ent(W_kc,   Wt_kvc,  1024, 1024, 1024, 1024, 0,  0);
    ent(W_vc,   Wt_kvc,  1024, 1024, 1024, 1024, 0,  1024);
    ent(W_oc,   Wt_oc,   1024, 1024, 1024, 1024, 0,  0);
    ent(W_gate, Wt_gu,   1024, 4096, 1024, 4096, 0,  0);
    ent(W_up,   Wt_gu,   1024, 4096, 1024, 4096, 0,  4096);
    ent(W_down, Wt_down, 4096, 1024, 4096, 1024, 0,  0);
    int total_tiles = 0;
    for (int j = 0; j < 13; j++) total_tiles += T.e[j].tiles;
    wtrans_all<<<total_tiles, 256, 0, stream>>>(T);
    f2bf_k<<<1024, 256, 0, stream>>>(memory, mem_bf, 1024 * 1024);

    // ---- phase 1: self-attention block
    rmsnorm_k<<<4096, 256, 0, stream>>>(x, n1w, hbuf);
    gemm_m128<5><<<dim3(1, 32, 4), 256, 0, stream>>>(hbuf, Wt_dqkv, cq32, nullptr, 4096, 128, 256, 1024, 1024, 128);
    cq_reduce<<<512, 256, 0, stream>>>(cq32, cq);
    qkuv_gemm<<<dim3(24, 32), 256, 0, stream>>>(cq, Wt_uqk, Wt_uv, qkb, vt);
    flash_self4<<<512, 256, 0, stream>>>(qkb, vt, ob);
    gemm_m128<1><<<dim3(8, 32), 256, 0, stream>>>(ob, Wt_os, x1, x, 4096, 1024, 1024, 1024, 1024, 1024);

    // ---- phase 2: cross attention block
    rmsnorm_k<<<4096, 256, 0, stream>>>(x1, n2w, hbuf);
    qckv_gemm<<<384, 256, 0, stream>>>(hbuf, Wt_qc, mem_bf, Wt_kvc, qcb, kvcb);
    cross_attn<<<dim3(4096, 4), 256, 0, stream>>>(qcb, kvcb, seg, ocb);
    gemm_m128<1><<<dim3(8, 32), 256, 0, stream>>>(ocb, Wt_oc, x2, x1, 4096, 1024, 1024, 1024, 1024, 1024);

    // ---- phase 3: FFN (fused gate+up+silu 256x256 pipelined, then down)
    rmsnorm_k<<<4096, 256, 0, stream>>>(x2, n3w, hbuf);
    ffn1_8ph<<<dim3(32, 16), 512, 0, stream>>>(hbuf, Wt_gu, gact);
    gemm_m128<1><<<dim3(8, 32), 256, 0, stream>>>(gact, Wt_down, (float*)d_out, x2, 4096, 1024, 4096, 4096, 4096, 1024);
}